// Round 10
// baseline (426.555 us; speedup 1.0000x reference)
//
#include <hip/hip_runtime.h>
#include <hip/hip_bf16.h>

#define N_IT 49999
#define NI   50000
#define HD   128
#define MNB  16
#define BSZ  512
#define LSEQ 50
#define G3   384

typedef __attribute__((ext_vector_type(8))) short short8;
typedef __attribute__((ext_vector_type(4))) float f32x4;
typedef __attribute__((ext_vector_type(16))) float f32x16;

__device__ __forceinline__ float sigmf(float x) {
  return 1.f / (1.f + __expf(-x));
}
__device__ __forceinline__ float fast_sigm(float x) {
  return __fdividef(1.f, 1.f + __expf(-x));
}
__device__ __forceinline__ float fast_tanh(float x) {
  float e = __expf(-2.f * x);
  return (1.f - e) * __fdividef(1.f, 1.f + e);
}

__device__ __forceinline__ unsigned short f2bf(float f) {
  unsigned u = __float_as_uint(f);
  u += 0x7FFF + ((u >> 16) & 1);
  return (unsigned short)(u >> 16);
}

// ---- DPP / swizzle butterfly helpers --------------------------------------
template <int CTRL>
__device__ __forceinline__ float dppadd(float v) {
  int s = __builtin_amdgcn_update_dpp(__float_as_int(v), __float_as_int(v),
                                      CTRL, 0xF, 0xF, false);
  return v + __int_as_float(s);
}
template <int MASK>
__device__ __forceinline__ float swzadd(float v) {
  return v + __int_as_float(__builtin_amdgcn_ds_swizzle(__float_as_int(v), MASK));
}
__device__ __forceinline__ float bp32add(float v) {
  int lane = threadIdx.x & 63;
  return v + __int_as_float(__builtin_amdgcn_ds_bpermute(((lane ^ 32) << 2),
                                                         __float_as_int(v)));
}

__device__ __forceinline__ float wsum(float v) {
  v = dppadd<0xB1>(v);    // i^1
  v = dppadd<0x4E>(v);    // i^2
  v = dppadd<0x141>(v);   // i^7 (row_half_mirror)
  v = dppadd<0x140>(v);   // i^15 (row_mirror)
  v = swzadd<0x401F>(v);  // i^16
  v = bp32add(v);         // i^32
  return v;
}

// ---------------- normalize rows; lane owns d={2l,2l+1}; fp32 + bf16x2 out --
__global__ void norm_kernel(const float* __restrict__ x, float* __restrict__ o,
                            unsigned* __restrict__ ob, int n) {
  int w = threadIdx.x >> 6, l = threadIdx.x & 63;
  int r = blockIdx.x * 4 + w;
  if (r >= n) return;
  float2 xv = *(const float2*)(x + (size_t)r * HD + 2 * l);
  float sq = wsum(xv.x * xv.x + xv.y * xv.y);
  float inv = 1.f / fmaxf(sqrtf(sq), 1e-12f);
  float a = xv.x * inv, b = xv.y * inv;
  *(float2*)(o + (size_t)r * HD + 2 * l) = make_float2(a, b);
  ob[(size_t)r * 64 + l] = (unsigned)f2bf(a) | ((unsigned)f2bf(b) << 16);
}

// ---------------- routing v3: Gram-matrix + MFMA ---------------------------
// One wave per node. u always = xs + Z^T c, so precompute G=Z Z^T and b=Z xs
// via 8 MFMAs, then 3 iterations of 16-dim algebra. z staged once in
// XOR-swizzled LDS for the final per-dim update.
__global__ __launch_bounds__(256) void routing_kernel(
    const float* __restrict__ xn, const unsigned* __restrict__ xnb,
    const int* __restrict__ adj, float* __restrict__ out) {
  __shared__ char zsh[4][4096];
  int tid = threadIdx.x;
  int w = tid >> 6, lane = tid & 63;
  int n = blockIdx.x * 4 + w;
  if (n >= N_IT) return;
  int m = lane & 15, quad = lane >> 4;
  const unsigned short* xb16 = (const unsigned short*)xnb;

  int idx = adj[n * MNB + m] - 1;
  const unsigned short* zrow = xb16 + (size_t)idx * HD;
  const unsigned short* xrow = xb16 + (size_t)n * HD;
  short8 zf[4], xf[4];
#pragma unroll
  for (int kk = 0; kk < 4; ++kk) {
    zf[kk] = *(const short8*)(zrow + kk * 32 + quad * 8);
    xf[kk] = *(const short8*)(xrow + kk * 32 + quad * 8);
  }
  // G[m][k] and b[m]; D-layout: lane holds row (quad*4+q), col (lane&15)
  f32x4 Gf = {0.f, 0.f, 0.f, 0.f}, Bv = {0.f, 0.f, 0.f, 0.f};
#pragma unroll
  for (int kk = 0; kk < 4; ++kk) {
    Gf = __builtin_amdgcn_mfma_f32_16x16x32_bf16(zf[kk], zf[kk], Gf, 0, 0, 0);
    Bv = __builtin_amdgcn_mfma_f32_16x16x32_bf16(zf[kk], xf[kk], Bv, 0, 0, 0);
  }
  // stage z in LDS (XOR-swizzled by row) for final update
  char* zb = zsh[w] + m * 256;
#pragma unroll
  for (int kk = 0; kk < 4; ++kk)
    *(short8*)(zb + ((kk * 64 + quad * 16) ^ ((m & 7) << 4))) = zf[kk];

  // c in row-form: pc[q] = c[quad*4+q]
  float pc0 = 0.0625f, pc1 = 0.0625f, pc2 = 0.0625f, pc3 = 0.0625f;
  int msel = lane & 3;
  int cjaddr = (((lane >> 2) & 3) << 4 | (lane & 3)) << 2;

#pragma unroll
  for (int it = 0; it < 3; ++it) {
    float selv = (msel == 0) ? pc0 : (msel == 1) ? pc1 : (msel == 2) ? pc2 : pc3;
    float cj = __int_as_float(
        __builtin_amdgcn_ds_bpermute(cjaddr, __float_as_int(selv)));
    float g0 = Gf[0] * cj, g1 = Gf[1] * cj, g2 = Gf[2] * cj, g3 = Gf[3] * cj;
    g0 = dppadd<0xB1>(g0); g1 = dppadd<0xB1>(g1); g2 = dppadd<0xB1>(g2); g3 = dppadd<0xB1>(g3);
    g0 = dppadd<0x4E>(g0); g1 = dppadd<0x4E>(g1); g2 = dppadd<0x4E>(g2); g3 = dppadd<0x4E>(g3);
    g0 = swzadd<0x101F>(g0); g1 = swzadd<0x101F>(g1); g2 = swzadd<0x101F>(g2); g3 = swzadd<0x101F>(g3);
    g0 = swzadd<0x201F>(g0); g1 = swzadd<0x201F>(g1); g2 = swzadd<0x201F>(g2); g3 = swzadd<0x201F>(g3);
    float t1 = pc0 * g0 + pc1 * g1 + pc2 * g2 + pc3 * g3;
    float t2 = pc0 * Bv[0] + pc1 * Bv[1] + pc2 * Bv[2] + pc3 * Bv[3];
    t1 = swzadd<0x401F>(t1); t1 = bp32add(t1);
    t2 = swzadd<0x401F>(t2); t2 = bp32add(t2);
    float sq = fmaxf(1.f + 2.f * t2 + t1, 0.f);
    float s = (sq / (sq + 1.f)) / fmaxf(sqrtf(sq), 1e-12f);
    float e0 = __expf(s * (Bv[0] + g0));
    float e1 = __expf(s * (Bv[1] + g1));
    float e2 = __expf(s * (Bv[2] + g2));
    float e3 = __expf(s * (Bv[3] + g3));
    float se = e0 + e1 + e2 + e3;
    se = swzadd<0x401F>(se); se = bp32add(se);
    float inv = __fdividef(1.f, se);
    pc0 = e0 * inv; pc1 = e1 * inv; pc2 = e2 * inv; pc3 = e3 * inv;
  }
  // final: u = xs + sum_m p[m] z[m]
  float selv = (msel == 0) ? pc0 : (msel == 1) ? pc1 : (msel == 2) ? pc2 : pc3;
  float2 xv = *(const float2*)(xn + (size_t)n * HD + 2 * lane);
  float u0 = xv.x, u1 = xv.y;
#pragma unroll
  for (int mm = 0; mm < MNB; ++mm) {
    int srcl = ((((mm >> 2) << 4) | (mm & 3)) << 2);
    float pm = __int_as_float(
        __builtin_amdgcn_ds_bpermute(srcl, __float_as_int(selv)));
    unsigned zv = *(const unsigned*)(zsh[w] + mm * 256 +
                                     ((4 * lane) ^ ((mm & 7) << 4)));
    float z0 = __int_as_float((zv & 0xFFFFu) << 16);
    float z1 = __int_as_float((zv >> 16) << 16);
    u0 += z0 * pm;
    u1 += z1 * pm;
  }
  *(float2*)(out + (size_t)n * HD + 2 * lane) = make_float2(u0, u1);
}

// ---------------- iv table (bf16 only): row0=0; rows 1..: LN1(x0+o1+o2) ----
__global__ void iv_kernel(const float* __restrict__ item_emb,
                          const float* __restrict__ o1, const float* __restrict__ o2,
                          const float* __restrict__ g, const float* __restrict__ bb,
                          unsigned short* __restrict__ tbf) {
  int w = threadIdx.x >> 6, l = threadIdx.x & 63;
  int r = blockIdx.x * 4 + w;
  if (r >= NI) return;
  if (r == 0) {
    tbf[l] = 0; tbf[l + 64] = 0;
    return;
  }
  size_t pr = (size_t)(r - 1) * HD;
  float a = item_emb[(size_t)r * HD + l]      + o1[pr + l]      + o2[pr + l];
  float b = item_emb[(size_t)r * HD + l + 64] + o1[pr + l + 64] + o2[pr + l + 64];
  float mu = wsum(a + b) * (1.f / HD);
  float v  = wsum(a * a + b * b) * (1.f / HD) - mu * mu;
  float rs = rsqrtf(v + 1e-5f);
  float va = (a - mu) * rs * g[l] + bb[l];
  float vb = (b - mu) * rs * g[l + 64] + bb[l + 64];
  tbf[(size_t)r * HD + l]      = f2bf(va);
  tbf[(size_t)r * HD + l + 64] = f2bf(vb);
}

// ---------------- cls table (bf16 only): LN3(prob_emb @ W_cls.T) -----------
__global__ void cls_kernel(const float* __restrict__ prob, const float* __restrict__ Wc,
                           const float* __restrict__ g, const float* __restrict__ bb,
                           unsigned short* __restrict__ cbf) {
  int w = threadIdx.x >> 6, l = threadIdx.x & 63;
  int r = blockIdx.x * 4 + w;
  if (r >= NI) return;
  float p[10];
#pragma unroll
  for (int k = 0; k < 10; ++k) p[k] = prob[(size_t)r * 10 + k];
  float a = 0.f, b = 0.f;
#pragma unroll
  for (int k = 0; k < 10; ++k) {
    a += p[k] * Wc[l * 10 + k];
    b += p[k] * Wc[(l + 64) * 10 + k];
  }
  float mu = wsum(a + b) * (1.f / HD);
  float v  = wsum(a * a + b * b) * (1.f / HD) - mu * mu;
  float rs = rsqrtf(v + 1e-5f);
  float va = (a - mu) * rs * g[l] + bb[l];
  float vb = (b - mu) * rs * g[l + 64] + bb[l + 64];
  cbf[(size_t)r * HD + l]      = f2bf(va);
  cbf[(size_t)r * HD + l + 64] = f2bf(vb);
}

// ---------------- Wih -> bf16 ----------------------------------------------
__global__ void wbf_kernel(const float* __restrict__ Wih,
                           unsigned short* __restrict__ wbf) {
  int i = blockIdx.x * 256 + threadIdx.x;
  if (i < 3 * HD * HD) wbf[i] = f2bf(Wih[i]);
}

// ---------------- gi via MFMA: gi[row][j] = dot(x_row, Wih[j]) (no bias) ---
__global__ __launch_bounds__(256) void gi2_kernel(
    const unsigned short* __restrict__ tbf, const unsigned short* __restrict__ cbf,
    const int* __restrict__ sess, const unsigned short* __restrict__ wbf,
    float* __restrict__ gi) {
  __shared__ int sidx[16];
  int tid = threadIdx.x;
  int row0 = blockIdx.x * 16;
  if (tid < 16) sidx[tid] = sess[(row0 + tid) % 25600];
  __syncthreads();
  const unsigned short* src = (row0 < 25600) ? tbf : cbf;
  int w = tid >> 6, lane = tid & 63;
  int rloc = lane & 15, quad = lane >> 4;
  int arow = sidx[rloc];
  int ko = quad * 8;
  short8 A[4];
#pragma unroll
  for (int kk = 0; kk < 4; ++kk)
    A[kk] = *(const short8*)(src + (size_t)arow * HD + kk * 32 + ko);
  float* gout = gi + (size_t)row0 * G3;
#pragma unroll
  for (int s = 0; s < 6; ++s) {
    int jt = w * 6 + s;
    int j = jt * 16 + rloc;
    f32x4 acc = {0.f, 0.f, 0.f, 0.f};
#pragma unroll
    for (int kk = 0; kk < 4; ++kk) {
      short8 B = *(const short8*)(wbf + (size_t)j * HD + kk * 32 + ko);
      acc = __builtin_amdgcn_mfma_f32_16x16x32_bf16(A[kk], B, acc, 0, 0, 0);
    }
#pragma unroll
    for (int q = 0; q < 4; ++q)
      gout[(size_t)(quad * 4 + q) * G3 + jt * 16 + rloc] = acc[q];
  }
}

// ---------------- GRU recurrence via MFMA ----------------------------------
__global__ __launch_bounds__(512) void gru_mfma_kernel(
    const float* __restrict__ gi_all, const float* __restrict__ Whh,
    const float* __restrict__ bih, const float* __restrict__ bhh,
    const int* __restrict__ lengths, float* __restrict__ ht_raw) {
  __shared__ unsigned short hlds[2][16 * HD];  // 8 KB
  int tid = threadIdx.x;
  int lane = tid & 63;
  int w = tid >> 6;
  int p = blockIdx.x >> 5;
  int r0 = (blockIdx.x & 31) * 16;
  int cN = lane & 15;
  int quad = lane >> 4;
  int d = w * 16 + cN;

  {
    int* hz = (int*)hlds;
    for (int i = tid; i < 2 * 16 * HD / 2; i += 512) hz[i] = 0;
  }

  short8 Br[4], Bz[4], Bn[4];
#pragma unroll
  for (int kk = 0; kk < 4; ++kk) {
    int kbase = quad * 8 + kk * 32;
    const float* wr_ = Whh + (size_t)d * HD + kbase;
    const float* wz_ = Whh + (size_t)(128 + d) * HD + kbase;
    const float* wn_ = Whh + (size_t)(256 + d) * HD + kbase;
    float4 r0v = *(const float4*)wr_, r1v = *(const float4*)(wr_ + 4);
    float4 z0v = *(const float4*)wz_, z1v = *(const float4*)(wz_ + 4);
    float4 n0v = *(const float4*)wn_, n1v = *(const float4*)(wn_ + 4);
    short8 br, bz, bn;
    br[0]=(short)f2bf(r0v.x); br[1]=(short)f2bf(r0v.y); br[2]=(short)f2bf(r0v.z); br[3]=(short)f2bf(r0v.w);
    br[4]=(short)f2bf(r1v.x); br[5]=(short)f2bf(r1v.y); br[6]=(short)f2bf(r1v.z); br[7]=(short)f2bf(r1v.w);
    bz[0]=(short)f2bf(z0v.x); bz[1]=(short)f2bf(z0v.y); bz[2]=(short)f2bf(z0v.z); bz[3]=(short)f2bf(z0v.w);
    bz[4]=(short)f2bf(z1v.x); bz[5]=(short)f2bf(z1v.y); bz[6]=(short)f2bf(z1v.z); bz[7]=(short)f2bf(z1v.w);
    bn[0]=(short)f2bf(n0v.x); bn[1]=(short)f2bf(n0v.y); bn[2]=(short)f2bf(n0v.z); bn[3]=(short)f2bf(n0v.w);
    bn[4]=(short)f2bf(n1v.x); bn[5]=(short)f2bf(n1v.y); bn[6]=(short)f2bf(n1v.z); bn[7]=(short)f2bf(n1v.w);
    Br[kk] = br; Bz[kk] = bz; Bn[kk] = bn;
  }
  float cr = bhh[d] + bih[d];
  float cz = bhh[128 + d] + bih[128 + d];
  float bhn = bhh[256 + d], bin = bih[256 + d];

  int lens4[4];
  float hold[4];
  const float* gptr[4];
#pragma unroll
  for (int gq = 0; gq < 4; ++gq) {
    int lr = quad * 4 + gq;
    lens4[gq] = lengths[r0 + lr] - 1;
    hold[gq] = 0.f;
    gptr[gq] = gi_all + ((size_t)p * 25600 + (size_t)(r0 + lr) * LSEQ) * G3 + d;
  }

  int aoff[4];
#pragma unroll
  for (int kk = 0; kk < 4; ++kk)
    aoff[kk] = cN * 256 + (((quad * 8 + kk * 32) * 2) ^ ((cN & 7) << 4));
  int woff[4];
#pragma unroll
  for (int gq = 0; gq < 4; ++gq) {
    int lr = quad * 4 + gq;
    woff[gq] = lr * 256 + ((2 * d) ^ ((lr & 7) << 4));
  }

  float giaR[4], giaZ[4], giaN[4];
#pragma unroll
  for (int gq = 0; gq < 4; ++gq) {
    giaR[gq] = gptr[gq][0];
    giaZ[gq] = gptr[gq][HD];
    giaN[gq] = gptr[gq][2 * HD];
  }
  __syncthreads();

  for (int t = 0; t < LSEQ; ++t) {
    float gbR[4], gbZ[4], gbN[4];
#pragma unroll
    for (int gq = 0; gq < 4; ++gq) {
      const float* gp = gptr[gq] + (size_t)(t + 1) * G3;
      gbR[gq] = gp[0]; gbZ[gq] = gp[HD]; gbN[gq] = gp[2 * HD];
    }
    const char* hb = (const char*)hlds[t & 1];
    f32x4 accR = {0.f, 0.f, 0.f, 0.f};
    f32x4 accZ = {0.f, 0.f, 0.f, 0.f};
    f32x4 accN = {0.f, 0.f, 0.f, 0.f};
#pragma unroll
    for (int kk = 0; kk < 4; ++kk) {
      short8 A = *(const short8*)(hb + aoff[kk]);
      accR = __builtin_amdgcn_mfma_f32_16x16x32_bf16(A, Br[kk], accR, 0, 0, 0);
      accZ = __builtin_amdgcn_mfma_f32_16x16x32_bf16(A, Bz[kk], accZ, 0, 0, 0);
      accN = __builtin_amdgcn_mfma_f32_16x16x32_bf16(A, Bn[kk], accN, 0, 0, 0);
    }
    char* hw = (char*)hlds[(t + 1) & 1];
#pragma unroll
    for (int gq = 0; gq < 4; ++gq) {
      float rg = fast_sigm(giaR[gq] + accR[gq] + cr);
      float zg = fast_sigm(giaZ[gq] + accZ[gq] + cz);
      float ng = fast_tanh(giaN[gq] + bin + rg * (accN[gq] + bhn));
      float hnew = (1.f - zg) * ng + zg * hold[gq];
      hold[gq] = hnew;
      *(unsigned short*)(hw + woff[gq]) = f2bf(hnew);
      if (t == lens4[gq])
        ht_raw[((size_t)p * BSZ + r0 + quad * 4 + gq) * HD + d] = hnew;
    }
    __syncthreads();
#pragma unroll
    for (int gq = 0; gq < 4; ++gq) {
      giaR[gq] = gbR[gq]; giaZ[gq] = gbZ[gq]; giaN[gq] = gbN[gq];
    }
  }
}

// ---------------- layernorm ht + bf16 copy ---------------------------------
__global__ void ln_ht_kernel(float* __restrict__ ht,
                             const float* __restrict__ g2, const float* __restrict__ b2,
                             const float* __restrict__ g4, const float* __restrict__ b4,
                             unsigned short* __restrict__ hbf) {
  int w = threadIdx.x >> 6, l = threadIdx.x & 63;
  int r = blockIdx.x * 4 + w;
  if (r >= 2 * BSZ) return;
  const float* g = (r < BSZ) ? g2 : g4;
  const float* bb = (r < BSZ) ? b2 : b4;
  float a = ht[(size_t)r * HD + l];
  float b = ht[(size_t)r * HD + l + 64];
  float mu = wsum(a + b) * (1.f / HD);
  float v  = wsum(a * a + b * b) * (1.f / HD) - mu * mu;
  float rs = rsqrtf(v + 1e-5f);
  float va = (a - mu) * rs * g[l] + bb[l];
  float vb = (b - mu) * rs * g[l + 64] + bb[l + 64];
  hbf[(size_t)r * HD + l]      = f2bf(va);
  hbf[(size_t)r * HD + l + 64] = f2bf(vb);
}

// ---------------- scores: 32x32x16 MFMA + XCD-swizzled grid ----------------
// ONLY change vs the R7-passing kernel: bijective blockIdx remap
// (grid 3136 = 8*392) so each XCD works a contiguous strip range (T1).
#define JW 256
__global__ __launch_bounds__(512) void scores2_kernel(
    const unsigned short* __restrict__ hbf,
    const unsigned short* __restrict__ tbf,
    const unsigned short* __restrict__ cbf,
    const float* __restrict__ a1p, const float* __restrict__ a2p,
    float* __restrict__ out) {
  __shared__ float s1l[32 * JW];
  __shared__ float s2l[32 * JW];
  int tid = threadIdx.x;
  int w = tid >> 6, lane = tid & 63;
  int bid = blockIdx.x;
  int wg = (bid & 7) * 392 + (bid >> 3);   // bijective: bid = (wg%392)*8 + wg/392
  int strip = wg >> 4;
  int r0b = (wg & 15) * 32;
  int j0 = strip * JW;
  int jc = j0 + w * 32 + (lane & 31);
  int jl = (jc < N_IT) ? jc : (N_IT - 1);
  int koA = (lane >> 5) * 8;

  f32x16 acc1 = {0.f}, acc2 = {0.f};
  const unsigned short* h1p = hbf + (size_t)(r0b + (lane & 31)) * HD + koA;
  const unsigned short* h2p = h1p + (size_t)BSZ * HD;
  const unsigned short* b1p = tbf + (size_t)(jl + 1) * HD + koA;
  const unsigned short* b2p = cbf + (size_t)(jl + 1) * HD + koA;
#pragma unroll
  for (int kk = 0; kk < 8; ++kk) {
    short8 A1 = *(const short8*)(h1p + kk * 16);
    short8 A2 = *(const short8*)(h2p + kk * 16);
    short8 B1 = *(const short8*)(b1p + kk * 16);
    short8 B2 = *(const short8*)(b2p + kk * 16);
    acc1 = __builtin_amdgcn_mfma_f32_32x32x16_bf16(A1, B1, acc1, 0, 0, 0);
    acc2 = __builtin_amdgcn_mfma_f32_32x32x16_bf16(A2, B2, acc2, 0, 0, 0);
  }
  int colb = w * 32 + (lane & 31);
#pragma unroll
  for (int q = 0; q < 16; ++q) {
    int row = (q & 3) + 8 * (q >> 2) + 4 * (lane >> 5);
    s1l[row * JW + colb] = acc1[q];
    s2l[row * JW + colb] = acc2[q];
  }
  __syncthreads();

  float sa1 = sigmf(a1p[0]);
  float sa2 = sigmf(a2p[0]);
  const size_t S = (size_t)BSZ * N_IT;
#pragma unroll
  for (int pss = 0; pss < 16; ++pss) {
    int idx = pss * 512 + tid;
    int row = idx >> 8;
    int jlc = idx & 255;
    int jg = j0 + jlc;
    if (jg < N_IT) {
      float s1 = s1l[idx];
      float s2 = s2l[idx];
      size_t o = (size_t)(r0b + row) * N_IT + jg;
      out[o]         = sa1 * s1 + sa2 * s2;
      out[S + o]     = s1;
      out[2 * S + o] = s2;
    }
  }
}

extern "C" void kernel_launch(void* const* d_in, const int* in_sizes, int n_in,
                              void* d_out, int out_size, void* d_ws, size_t ws_size,
                              hipStream_t stream) {
  const float* item_emb = (const float*)d_in[0];
  const float* prob_emb = (const float*)d_in[1];
  const float* W_cls    = (const float*)d_in[2];
  const float* a1       = (const float*)d_in[3];
  const float* a2       = (const float*)d_in[4];
  const float* Wih      = (const float*)d_in[5];
  const float* Whh      = (const float*)d_in[6];
  const float* bih      = (const float*)d_in[7];
  const float* bhh      = (const float*)d_in[8];
  const float* ln1_g = (const float*)d_in[9];
  const float* ln1_b = (const float*)d_in[10];
  const float* ln2_g = (const float*)d_in[11];
  const float* ln2_b = (const float*)d_in[12];
  const float* ln3_g = (const float*)d_in[13];
  const float* ln3_b = (const float*)d_in[14];
  const float* ln4_g = (const float*)d_in[15];
  const float* ln4_b = (const float*)d_in[16];
  const int* inp_sess = (const int*)d_in[19];
  const int* lengths  = (const int*)d_in[20];
  const int* adj      = (const int*)d_in[21];
  float* out = (float*)d_out;

  float* ws = (float*)d_ws;
  const size_t SZ_ROW = (size_t)N_IT * HD;
  float* xn  = ws;
  float* o1  = xn + SZ_ROW;
  float* o2  = o1 + SZ_ROW;
  float* gi  = o2 + SZ_ROW + 2 * (size_t)NI * HD;
  float* htb = gi + (size_t)2 * 25600 * G3;

  // aliases into dead regions (exactly as the R7-passing kernel):
  unsigned* xnb = (unsigned*)gi;                    // dead before gi2 writes gi
  unsigned short* tbf = (unsigned short*)xn;        // written by iv (xn dead after hop2)
  unsigned short* cbf = (unsigned short*)o2;        // written by cls (o2 dead after iv)
  unsigned short* hbf = (unsigned short*)o1;        // written by ln_ht (o1 dead after iv)
  unsigned short* wbf = (unsigned short*)(o2 + 3400000);  // past cbf

  int nb4 = (N_IT + 3) / 4;
  int nb4i = (NI + 3) / 4;

  norm_kernel<<<nb4, 256, 0, stream>>>(item_emb + HD, xn, xnb, N_IT);
  routing_kernel<<<nb4, 256, 0, stream>>>(xn, xnb, adj + MNB, o1);
  norm_kernel<<<nb4, 256, 0, stream>>>(o1, xn, xnb, N_IT);
  routing_kernel<<<nb4, 256, 0, stream>>>(xn, xnb, adj + MNB, o2);
  iv_kernel<<<nb4i, 256, 0, stream>>>(item_emb, o1, o2, ln1_g, ln1_b, tbf);
  cls_kernel<<<nb4i, 256, 0, stream>>>(prob_emb, W_cls, ln3_g, ln3_b, cbf);
  wbf_kernel<<<192, 256, 0, stream>>>(Wih, wbf);
  gi2_kernel<<<3200, 256, 0, stream>>>(tbf, cbf, inp_sess, wbf, gi);
  gru_mfma_kernel<<<64, 512, 0, stream>>>(gi, Whh, bih, bhh, lengths, htb);
  ln_ht_kernel<<<256, 256, 0, stream>>>(htb, ln2_g, ln2_b, ln4_g, ln4_b, hbf);
  scores2_kernel<<<196 * 16, 512, 0, stream>>>(hbf, tbf, cbf, a1, a2, out);
}

// Round 12
// 417.842 us; speedup vs baseline: 1.0209x; 1.0209x over previous
//
#include <hip/hip_runtime.h>
#include <hip/hip_bf16.h>

#define N_IT 49999
#define NI   50000
#define HD   128
#define MNB  16
#define BSZ  512
#define LSEQ 50
#define G3   384

typedef __attribute__((ext_vector_type(8))) short short8;
typedef __attribute__((ext_vector_type(4))) float f32x4;
typedef __attribute__((ext_vector_type(16))) float f32x16;

__device__ __forceinline__ float sigmf(float x) {
  return 1.f / (1.f + __expf(-x));
}
__device__ __forceinline__ float fast_sigm(float x) {
  return __fdividef(1.f, 1.f + __expf(-x));
}
__device__ __forceinline__ float fast_tanh(float x) {
  float e = __expf(-2.f * x);
  return (1.f - e) * __fdividef(1.f, 1.f + e);
}

__device__ __forceinline__ unsigned short f2bf(float f) {
  unsigned u = __float_as_uint(f);
  u += 0x7FFF + ((u >> 16) & 1);
  return (unsigned short)(u >> 16);
}

// ---- DPP / swizzle butterfly helpers --------------------------------------
template <int CTRL>
__device__ __forceinline__ float dppadd(float v) {
  int s = __builtin_amdgcn_update_dpp(__float_as_int(v), __float_as_int(v),
                                      CTRL, 0xF, 0xF, false);
  return v + __int_as_float(s);
}
template <int MASK>
__device__ __forceinline__ float swzadd(float v) {
  return v + __int_as_float(__builtin_amdgcn_ds_swizzle(__float_as_int(v), MASK));
}
__device__ __forceinline__ float bp32add(float v) {
  int lane = threadIdx.x & 63;
  return v + __int_as_float(__builtin_amdgcn_ds_bpermute(((lane ^ 32) << 2),
                                                         __float_as_int(v)));
}

__device__ __forceinline__ float wsum(float v) {
  v = dppadd<0xB1>(v);    // i^1
  v = dppadd<0x4E>(v);    // i^2
  v = dppadd<0x141>(v);   // i^7 (row_half_mirror)
  v = dppadd<0x140>(v);   // i^15 (row_mirror)
  v = swzadd<0x401F>(v);  // i^16
  v = bp32add(v);         // i^32
  return v;
}

// ---------------- normalize rows; lane owns d={2l,2l+1}; fp32 + bf16x2 out --
__global__ void norm_kernel(const float* __restrict__ x, float* __restrict__ o,
                            unsigned* __restrict__ ob, int n) {
  int w = threadIdx.x >> 6, l = threadIdx.x & 63;
  int r = blockIdx.x * 4 + w;
  if (r >= n) return;
  float2 xv = *(const float2*)(x + (size_t)r * HD + 2 * l);
  float sq = wsum(xv.x * xv.x + xv.y * xv.y);
  float inv = 1.f / fmaxf(sqrtf(sq), 1e-12f);
  float a = xv.x * inv, b = xv.y * inv;
  *(float2*)(o + (size_t)r * HD + 2 * l) = make_float2(a, b);
  ob[(size_t)r * 64 + l] = (unsigned)f2bf(a) | ((unsigned)f2bf(b) << 16);
}

// ---------------- routing hop1 + fused normalize epilogue ------------------
// Body is the R7-passing routing_kernel VERBATIM; appended epilogue writes
// the normalized result to SEPARATE buffers onf/onb (no alias with inputs).
__global__ __launch_bounds__(256) void routing1_kernel(
    const float* __restrict__ xn, const unsigned* __restrict__ xnb,
    const int* __restrict__ adj, float* __restrict__ out,
    float* __restrict__ onf, unsigned* __restrict__ onb) {
  __shared__ char zsh[4][4096];
  int tid = threadIdx.x;
  int w = tid >> 6, lane = tid & 63;
  int n = blockIdx.x * 4 + w;
  if (n >= N_IT) return;
  int m = lane & 15, quad = lane >> 4;
  const unsigned short* xb16 = (const unsigned short*)xnb;

  int idx = adj[n * MNB + m] - 1;
  const unsigned short* zrow = xb16 + (size_t)idx * HD;
  const unsigned short* xrow = xb16 + (size_t)n * HD;
  short8 zf[4], xf[4];
#pragma unroll
  for (int kk = 0; kk < 4; ++kk) {
    zf[kk] = *(const short8*)(zrow + kk * 32 + quad * 8);
    xf[kk] = *(const short8*)(xrow + kk * 32 + quad * 8);
  }
  f32x4 Gf = {0.f, 0.f, 0.f, 0.f}, Bv = {0.f, 0.f, 0.f, 0.f};
#pragma unroll
  for (int kk = 0; kk < 4; ++kk) {
    Gf = __builtin_amdgcn_mfma_f32_16x16x32_bf16(zf[kk], zf[kk], Gf, 0, 0, 0);
    Bv = __builtin_amdgcn_mfma_f32_16x16x32_bf16(zf[kk], xf[kk], Bv, 0, 0, 0);
  }
  char* zb = zsh[w] + m * 256;
#pragma unroll
  for (int kk = 0; kk < 4; ++kk)
    *(short8*)(zb + ((kk * 64 + quad * 16) ^ ((m & 7) << 4))) = zf[kk];

  float pc0 = 0.0625f, pc1 = 0.0625f, pc2 = 0.0625f, pc3 = 0.0625f;
  int msel = lane & 3;
  int cjaddr = (((lane >> 2) & 3) << 4 | (lane & 3)) << 2;

#pragma unroll
  for (int it = 0; it < 3; ++it) {
    float selv = (msel == 0) ? pc0 : (msel == 1) ? pc1 : (msel == 2) ? pc2 : pc3;
    float cj = __int_as_float(
        __builtin_amdgcn_ds_bpermute(cjaddr, __float_as_int(selv)));
    float g0 = Gf[0] * cj, g1 = Gf[1] * cj, g2 = Gf[2] * cj, g3 = Gf[3] * cj;
    g0 = dppadd<0xB1>(g0); g1 = dppadd<0xB1>(g1); g2 = dppadd<0xB1>(g2); g3 = dppadd<0xB1>(g3);
    g0 = dppadd<0x4E>(g0); g1 = dppadd<0x4E>(g1); g2 = dppadd<0x4E>(g2); g3 = dppadd<0x4E>(g3);
    g0 = swzadd<0x101F>(g0); g1 = swzadd<0x101F>(g1); g2 = swzadd<0x101F>(g2); g3 = swzadd<0x101F>(g3);
    g0 = swzadd<0x201F>(g0); g1 = swzadd<0x201F>(g1); g2 = swzadd<0x201F>(g2); g3 = swzadd<0x201F>(g3);
    float t1 = pc0 * g0 + pc1 * g1 + pc2 * g2 + pc3 * g3;
    float t2 = pc0 * Bv[0] + pc1 * Bv[1] + pc2 * Bv[2] + pc3 * Bv[3];
    t1 = swzadd<0x401F>(t1); t1 = bp32add(t1);
    t2 = swzadd<0x401F>(t2); t2 = bp32add(t2);
    float sq = fmaxf(1.f + 2.f * t2 + t1, 0.f);
    float s = (sq / (sq + 1.f)) / fmaxf(sqrtf(sq), 1e-12f);
    float e0 = __expf(s * (Bv[0] + g0));
    float e1 = __expf(s * (Bv[1] + g1));
    float e2 = __expf(s * (Bv[2] + g2));
    float e3 = __expf(s * (Bv[3] + g3));
    float se = e0 + e1 + e2 + e3;
    se = swzadd<0x401F>(se); se = bp32add(se);
    float inv = __fdividef(1.f, se);
    pc0 = e0 * inv; pc1 = e1 * inv; pc2 = e2 * inv; pc3 = e3 * inv;
  }
  float selv = (msel == 0) ? pc0 : (msel == 1) ? pc1 : (msel == 2) ? pc2 : pc3;
  float2 xv = *(const float2*)(xn + (size_t)n * HD + 2 * lane);
  float u0 = xv.x, u1 = xv.y;
#pragma unroll
  for (int mm = 0; mm < MNB; ++mm) {
    int srcl = ((((mm >> 2) << 4) | (mm & 3)) << 2);
    float pm = __int_as_float(
        __builtin_amdgcn_ds_bpermute(srcl, __float_as_int(selv)));
    unsigned zv = *(const unsigned*)(zsh[w] + mm * 256 +
                                     ((4 * lane) ^ ((mm & 7) << 4)));
    float z0 = __int_as_float((zv & 0xFFFFu) << 16);
    float z1 = __int_as_float((zv >> 16) << 16);
    u0 += z0 * pm;
    u1 += z1 * pm;
  }
  *(float2*)(out + (size_t)n * HD + 2 * lane) = make_float2(u0, u1);
  // fused normalize (was norm_kernel#2), to SEPARATE buffers
  float nsq = wsum(u0 * u0 + u1 * u1);
  float ninv = 1.f / fmaxf(sqrtf(nsq), 1e-12f);
  float na = u0 * ninv, nb = u1 * ninv;
  *(float2*)(onf + (size_t)n * HD + 2 * lane) = make_float2(na, nb);
  onb[(size_t)n * 64 + lane] = (unsigned)f2bf(na) | ((unsigned)f2bf(nb) << 16);
}

// ---------------- routing v3 (hop2): R7 verbatim ---------------------------
__global__ __launch_bounds__(256) void routing_kernel(
    const float* __restrict__ xn, const unsigned* __restrict__ xnb,
    const int* __restrict__ adj, float* __restrict__ out) {
  __shared__ char zsh[4][4096];
  int tid = threadIdx.x;
  int w = tid >> 6, lane = tid & 63;
  int n = blockIdx.x * 4 + w;
  if (n >= N_IT) return;
  int m = lane & 15, quad = lane >> 4;
  const unsigned short* xb16 = (const unsigned short*)xnb;

  int idx = adj[n * MNB + m] - 1;
  const unsigned short* zrow = xb16 + (size_t)idx * HD;
  const unsigned short* xrow = xb16 + (size_t)n * HD;
  short8 zf[4], xf[4];
#pragma unroll
  for (int kk = 0; kk < 4; ++kk) {
    zf[kk] = *(const short8*)(zrow + kk * 32 + quad * 8);
    xf[kk] = *(const short8*)(xrow + kk * 32 + quad * 8);
  }
  f32x4 Gf = {0.f, 0.f, 0.f, 0.f}, Bv = {0.f, 0.f, 0.f, 0.f};
#pragma unroll
  for (int kk = 0; kk < 4; ++kk) {
    Gf = __builtin_amdgcn_mfma_f32_16x16x32_bf16(zf[kk], zf[kk], Gf, 0, 0, 0);
    Bv = __builtin_amdgcn_mfma_f32_16x16x32_bf16(zf[kk], xf[kk], Bv, 0, 0, 0);
  }
  char* zb = zsh[w] + m * 256;
#pragma unroll
  for (int kk = 0; kk < 4; ++kk)
    *(short8*)(zb + ((kk * 64 + quad * 16) ^ ((m & 7) << 4))) = zf[kk];

  float pc0 = 0.0625f, pc1 = 0.0625f, pc2 = 0.0625f, pc3 = 0.0625f;
  int msel = lane & 3;
  int cjaddr = (((lane >> 2) & 3) << 4 | (lane & 3)) << 2;

#pragma unroll
  for (int it = 0; it < 3; ++it) {
    float selv = (msel == 0) ? pc0 : (msel == 1) ? pc1 : (msel == 2) ? pc2 : pc3;
    float cj = __int_as_float(
        __builtin_amdgcn_ds_bpermute(cjaddr, __float_as_int(selv)));
    float g0 = Gf[0] * cj, g1 = Gf[1] * cj, g2 = Gf[2] * cj, g3 = Gf[3] * cj;
    g0 = dppadd<0xB1>(g0); g1 = dppadd<0xB1>(g1); g2 = dppadd<0xB1>(g2); g3 = dppadd<0xB1>(g3);
    g0 = dppadd<0x4E>(g0); g1 = dppadd<0x4E>(g1); g2 = dppadd<0x4E>(g2); g3 = dppadd<0x4E>(g3);
    g0 = swzadd<0x101F>(g0); g1 = swzadd<0x101F>(g1); g2 = swzadd<0x101F>(g2); g3 = swzadd<0x101F>(g3);
    g0 = swzadd<0x201F>(g0); g1 = swzadd<0x201F>(g1); g2 = swzadd<0x201F>(g2); g3 = swzadd<0x201F>(g3);
    float t1 = pc0 * g0 + pc1 * g1 + pc2 * g2 + pc3 * g3;
    float t2 = pc0 * Bv[0] + pc1 * Bv[1] + pc2 * Bv[2] + pc3 * Bv[3];
    t1 = swzadd<0x401F>(t1); t1 = bp32add(t1);
    t2 = swzadd<0x401F>(t2); t2 = bp32add(t2);
    float sq = fmaxf(1.f + 2.f * t2 + t1, 0.f);
    float s = (sq / (sq + 1.f)) / fmaxf(sqrtf(sq), 1e-12f);
    float e0 = __expf(s * (Bv[0] + g0));
    float e1 = __expf(s * (Bv[1] + g1));
    float e2 = __expf(s * (Bv[2] + g2));
    float e3 = __expf(s * (Bv[3] + g3));
    float se = e0 + e1 + e2 + e3;
    se = swzadd<0x401F>(se); se = bp32add(se);
    float inv = __fdividef(1.f, se);
    pc0 = e0 * inv; pc1 = e1 * inv; pc2 = e2 * inv; pc3 = e3 * inv;
  }
  float selv = (msel == 0) ? pc0 : (msel == 1) ? pc1 : (msel == 2) ? pc2 : pc3;
  float2 xv = *(const float2*)(xn + (size_t)n * HD + 2 * lane);
  float u0 = xv.x, u1 = xv.y;
#pragma unroll
  for (int mm = 0; mm < MNB; ++mm) {
    int srcl = ((((mm >> 2) << 4) | (mm & 3)) << 2);
    float pm = __int_as_float(
        __builtin_amdgcn_ds_bpermute(srcl, __float_as_int(selv)));
    unsigned zv = *(const unsigned*)(zsh[w] + mm * 256 +
                                     ((4 * lane) ^ ((mm & 7) << 4)));
    float z0 = __int_as_float((zv & 0xFFFFu) << 16);
    float z1 = __int_as_float((zv >> 16) << 16);
    u0 += z0 * pm;
    u1 += z1 * pm;
  }
  *(float2*)(out + (size_t)n * HD + 2 * lane) = make_float2(u0, u1);
}

// ---------------- iv table (bf16 only): row0=0; rows 1..: LN1(x0+o1+o2) ----
__global__ void iv_kernel(const float* __restrict__ item_emb,
                          const float* __restrict__ o1, const float* __restrict__ o2,
                          const float* __restrict__ g, const float* __restrict__ bb,
                          unsigned short* __restrict__ tbf) {
  int w = threadIdx.x >> 6, l = threadIdx.x & 63;
  int r = blockIdx.x * 4 + w;
  if (r >= NI) return;
  if (r == 0) {
    tbf[l] = 0; tbf[l + 64] = 0;
    return;
  }
  size_t pr = (size_t)(r - 1) * HD;
  float a = item_emb[(size_t)r * HD + l]      + o1[pr + l]      + o2[pr + l];
  float b = item_emb[(size_t)r * HD + l + 64] + o1[pr + l + 64] + o2[pr + l + 64];
  float mu = wsum(a + b) * (1.f / HD);
  float v  = wsum(a * a + b * b) * (1.f / HD) - mu * mu;
  float rs = rsqrtf(v + 1e-5f);
  float va = (a - mu) * rs * g[l] + bb[l];
  float vb = (b - mu) * rs * g[l + 64] + bb[l + 64];
  tbf[(size_t)r * HD + l]      = f2bf(va);
  tbf[(size_t)r * HD + l + 64] = f2bf(vb);
}

// ---------------- cls table (bf16 only): LN3(prob_emb @ W_cls.T) -----------
__global__ void cls_kernel(const float* __restrict__ prob, const float* __restrict__ Wc,
                           const float* __restrict__ g, const float* __restrict__ bb,
                           unsigned short* __restrict__ cbf) {
  int w = threadIdx.x >> 6, l = threadIdx.x & 63;
  int r = blockIdx.x * 4 + w;
  if (r >= NI) return;
  float p[10];
#pragma unroll
  for (int k = 0; k < 10; ++k) p[k] = prob[(size_t)r * 10 + k];
  float a = 0.f, b = 0.f;
#pragma unroll
  for (int k = 0; k < 10; ++k) {
    a += p[k] * Wc[l * 10 + k];
    b += p[k] * Wc[(l + 64) * 10 + k];
  }
  float mu = wsum(a + b) * (1.f / HD);
  float v  = wsum(a * a + b * b) * (1.f / HD) - mu * mu;
  float rs = rsqrtf(v + 1e-5f);
  float va = (a - mu) * rs * g[l] + bb[l];
  float vb = (b - mu) * rs * g[l + 64] + bb[l + 64];
  cbf[(size_t)r * HD + l]      = f2bf(va);
  cbf[(size_t)r * HD + l + 64] = f2bf(vb);
}

// ---------------- Wih -> bf16 ----------------------------------------------
__global__ void wbf_kernel(const float* __restrict__ Wih,
                           unsigned short* __restrict__ wbf) {
  int i = blockIdx.x * 256 + threadIdx.x;
  if (i < 3 * HD * HD) wbf[i] = f2bf(Wih[i]);
}

// ---------------- gi via MFMA: gi[row][j] = dot(x_row, Wih[j]) (no bias) ---
__global__ __launch_bounds__(256) void gi2_kernel(
    const unsigned short* __restrict__ tbf, const unsigned short* __restrict__ cbf,
    const int* __restrict__ sess, const unsigned short* __restrict__ wbf,
    float* __restrict__ gi) {
  __shared__ int sidx[16];
  int tid = threadIdx.x;
  int row0 = blockIdx.x * 16;
  if (tid < 16) sidx[tid] = sess[(row0 + tid) % 25600];
  __syncthreads();
  const unsigned short* src = (row0 < 25600) ? tbf : cbf;
  int w = tid >> 6, lane = tid & 63;
  int rloc = lane & 15, quad = lane >> 4;
  int arow = sidx[rloc];
  int ko = quad * 8;
  short8 A[4];
#pragma unroll
  for (int kk = 0; kk < 4; ++kk)
    A[kk] = *(const short8*)(src + (size_t)arow * HD + kk * 32 + ko);
  float* gout = gi + (size_t)row0 * G3;
#pragma unroll
  for (int s = 0; s < 6; ++s) {
    int jt = w * 6 + s;
    int j = jt * 16 + rloc;
    f32x4 acc = {0.f, 0.f, 0.f, 0.f};
#pragma unroll
    for (int kk = 0; kk < 4; ++kk) {
      short8 B = *(const short8*)(wbf + (size_t)j * HD + kk * 32 + ko);
      acc = __builtin_amdgcn_mfma_f32_16x16x32_bf16(A[kk], B, acc, 0, 0, 0);
    }
#pragma unroll
    for (int q = 0; q < 4; ++q)
      gout[(size_t)(quad * 4 + q) * G3 + jt * 16 + rloc] = acc[q];
  }
}

// ---------------- GRU recurrence via MFMA ----------------------------------
__global__ __launch_bounds__(512) void gru_mfma_kernel(
    const float* __restrict__ gi_all, const float* __restrict__ Whh,
    const float* __restrict__ bih, const float* __restrict__ bhh,
    const int* __restrict__ lengths, float* __restrict__ ht_raw) {
  __shared__ unsigned short hlds[2][16 * HD];  // 8 KB
  int tid = threadIdx.x;
  int lane = tid & 63;
  int w = tid >> 6;
  int p = blockIdx.x >> 5;
  int r0 = (blockIdx.x & 31) * 16;
  int cN = lane & 15;
  int quad = lane >> 4;
  int d = w * 16 + cN;

  {
    int* hz = (int*)hlds;
    for (int i = tid; i < 2 * 16 * HD / 2; i += 512) hz[i] = 0;
  }

  short8 Br[4], Bz[4], Bn[4];
#pragma unroll
  for (int kk = 0; kk < 4; ++kk) {
    int kbase = quad * 8 + kk * 32;
    const float* wr_ = Whh + (size_t)d * HD + kbase;
    const float* wz_ = Whh + (size_t)(128 + d) * HD + kbase;
    const float* wn_ = Whh + (size_t)(256 + d) * HD + kbase;
    float4 r0v = *(const float4*)wr_, r1v = *(const float4*)(wr_ + 4);
    float4 z0v = *(const float4*)wz_, z1v = *(const float4*)(wz_ + 4);
    float4 n0v = *(const float4*)wn_, n1v = *(const float4*)(wn_ + 4);
    short8 br, bz, bn;
    br[0]=(short)f2bf(r0v.x); br[1]=(short)f2bf(r0v.y); br[2]=(short)f2bf(r0v.z); br[3]=(short)f2bf(r0v.w);
    br[4]=(short)f2bf(r1v.x); br[5]=(short)f2bf(r1v.y); br[6]=(short)f2bf(r1v.z); br[7]=(short)f2bf(r1v.w);
    bz[0]=(short)f2bf(z0v.x); bz[1]=(short)f2bf(z0v.y); bz[2]=(short)f2bf(z0v.z); bz[3]=(short)f2bf(z0v.w);
    bz[4]=(short)f2bf(z1v.x); bz[5]=(short)f2bf(z1v.y); bz[6]=(short)f2bf(z1v.z); bz[7]=(short)f2bf(z1v.w);
    bn[0]=(short)f2bf(n0v.x); bn[1]=(short)f2bf(n0v.y); bn[2]=(short)f2bf(n0v.z); bn[3]=(short)f2bf(n0v.w);
    bn[4]=(short)f2bf(n1v.x); bn[5]=(short)f2bf(n1v.y); bn[6]=(short)f2bf(n1v.z); bn[7]=(short)f2bf(n1v.w);
    Br[kk] = br; Bz[kk] = bz; Bn[kk] = bn;
  }
  float cr = bhh[d] + bih[d];
  float cz = bhh[128 + d] + bih[128 + d];
  float bhn = bhh[256 + d], bin = bih[256 + d];

  int lens4[4];
  float hold[4];
  const float* gptr[4];
#pragma unroll
  for (int gq = 0; gq < 4; ++gq) {
    int lr = quad * 4 + gq;
    lens4[gq] = lengths[r0 + lr] - 1;
    hold[gq] = 0.f;
    gptr[gq] = gi_all + ((size_t)p * 25600 + (size_t)(r0 + lr) * LSEQ) * G3 + d;
  }

  int aoff[4];
#pragma unroll
  for (int kk = 0; kk < 4; ++kk)
    aoff[kk] = cN * 256 + (((quad * 8 + kk * 32) * 2) ^ ((cN & 7) << 4));
  int woff[4];
#pragma unroll
  for (int gq = 0; gq < 4; ++gq) {
    int lr = quad * 4 + gq;
    woff[gq] = lr * 256 + ((2 * d) ^ ((lr & 7) << 4));
  }

  float giaR[4], giaZ[4], giaN[4];
#pragma unroll
  for (int gq = 0; gq < 4; ++gq) {
    giaR[gq] = gptr[gq][0];
    giaZ[gq] = gptr[gq][HD];
    giaN[gq] = gptr[gq][2 * HD];
  }
  __syncthreads();

  for (int t = 0; t < LSEQ; ++t) {
    float gbR[4], gbZ[4], gbN[4];
#pragma unroll
    for (int gq = 0; gq < 4; ++gq) {
      const float* gp = gptr[gq] + (size_t)(t + 1) * G3;
      gbR[gq] = gp[0]; gbZ[gq] = gp[HD]; gbN[gq] = gp[2 * HD];
    }
    const char* hb = (const char*)hlds[t & 1];
    f32x4 accR = {0.f, 0.f, 0.f, 0.f};
    f32x4 accZ = {0.f, 0.f, 0.f, 0.f};
    f32x4 accN = {0.f, 0.f, 0.f, 0.f};
#pragma unroll
    for (int kk = 0; kk < 4; ++kk) {
      short8 A = *(const short8*)(hb + aoff[kk]);
      accR = __builtin_amdgcn_mfma_f32_16x16x32_bf16(A, Br[kk], accR, 0, 0, 0);
      accZ = __builtin_amdgcn_mfma_f32_16x16x32_bf16(A, Bz[kk], accZ, 0, 0, 0);
      accN = __builtin_amdgcn_mfma_f32_16x16x32_bf16(A, Bn[kk], accN, 0, 0, 0);
    }
    char* hw = (char*)hlds[(t + 1) & 1];
#pragma unroll
    for (int gq = 0; gq < 4; ++gq) {
      float rg = fast_sigm(giaR[gq] + accR[gq] + cr);
      float zg = fast_sigm(giaZ[gq] + accZ[gq] + cz);
      float ng = fast_tanh(giaN[gq] + bin + rg * (accN[gq] + bhn));
      float hnew = (1.f - zg) * ng + zg * hold[gq];
      hold[gq] = hnew;
      *(unsigned short*)(hw + woff[gq]) = f2bf(hnew);
      if (t == lens4[gq])
        ht_raw[((size_t)p * BSZ + r0 + quad * 4 + gq) * HD + d] = hnew;
    }
    __syncthreads();
#pragma unroll
    for (int gq = 0; gq < 4; ++gq) {
      giaR[gq] = gbR[gq]; giaZ[gq] = gbZ[gq]; giaN[gq] = gbN[gq];
    }
  }
}

// ---------------- layernorm ht + bf16 copy ---------------------------------
__global__ void ln_ht_kernel(const float* __restrict__ ht,
                             const float* __restrict__ g2, const float* __restrict__ b2,
                             const float* __restrict__ g4, const float* __restrict__ b4,
                             unsigned short* __restrict__ hbf) {
  int w = threadIdx.x >> 6, l = threadIdx.x & 63;
  int r = blockIdx.x * 4 + w;
  if (r >= 2 * BSZ) return;
  const float* g = (r < BSZ) ? g2 : g4;
  const float* bb = (r < BSZ) ? b2 : b4;
  float a = ht[(size_t)r * HD + l];
  float b = ht[(size_t)r * HD + l + 64];
  float mu = wsum(a + b) * (1.f / HD);
  float v  = wsum(a * a + b * b) * (1.f / HD) - mu * mu;
  float rs = rsqrtf(v + 1e-5f);
  float va = (a - mu) * rs * g[l] + bb[l];
  float vb = (b - mu) * rs * g[l + 64] + bb[l + 64];
  hbf[(size_t)r * HD + l]      = f2bf(va);
  hbf[(size_t)r * HD + l + 64] = f2bf(vb);
}

// ---------------- scores: 32x32x16 MFMA + LDS-staged contiguous stores -----
#define JW 256
__global__ __launch_bounds__(512) void scores2_kernel(
    const unsigned short* __restrict__ hbf,
    const unsigned short* __restrict__ tbf,
    const unsigned short* __restrict__ cbf,
    const float* __restrict__ a1p, const float* __restrict__ a2p,
    float* __restrict__ out) {
  __shared__ float s1l[32 * JW];
  __shared__ float s2l[32 * JW];
  int tid = threadIdx.x;
  int w = tid >> 6, lane = tid & 63;
  int strip = blockIdx.x >> 4;
  int r0b = (blockIdx.x & 15) * 32;
  int j0 = strip * JW;
  int jc = j0 + w * 32 + (lane & 31);
  int jl = (jc < N_IT) ? jc : (N_IT - 1);
  int koA = (lane >> 5) * 8;

  f32x16 acc1 = {0.f}, acc2 = {0.f};
  const unsigned short* h1p = hbf + (size_t)(r0b + (lane & 31)) * HD + koA;
  const unsigned short* h2p = h1p + (size_t)BSZ * HD;
  const unsigned short* b1p = tbf + (size_t)(jl + 1) * HD + koA;
  const unsigned short* b2p = cbf + (size_t)(jl + 1) * HD + koA;
#pragma unroll
  for (int kk = 0; kk < 8; ++kk) {
    short8 A1 = *(const short8*)(h1p + kk * 16);
    short8 A2 = *(const short8*)(h2p + kk * 16);
    short8 B1 = *(const short8*)(b1p + kk * 16);
    short8 B2 = *(const short8*)(b2p + kk * 16);
    acc1 = __builtin_amdgcn_mfma_f32_32x32x16_bf16(A1, B1, acc1, 0, 0, 0);
    acc2 = __builtin_amdgcn_mfma_f32_32x32x16_bf16(A2, B2, acc2, 0, 0, 0);
  }
  int colb = w * 32 + (lane & 31);
#pragma unroll
  for (int q = 0; q < 16; ++q) {
    int row = (q & 3) + 8 * (q >> 2) + 4 * (lane >> 5);
    s1l[row * JW + colb] = acc1[q];
    s2l[row * JW + colb] = acc2[q];
  }
  __syncthreads();

  float sa1 = sigmf(a1p[0]);
  float sa2 = sigmf(a2p[0]);
  const size_t S = (size_t)BSZ * N_IT;
#pragma unroll
  for (int pss = 0; pss < 16; ++pss) {
    int idx = pss * 512 + tid;
    int row = idx >> 8;
    int jlc = idx & 255;
    int jg = j0 + jlc;
    if (jg < N_IT) {
      float s1 = s1l[idx];
      float s2 = s2l[idx];
      size_t o = (size_t)(r0b + row) * N_IT + jg;
      out[o]         = sa1 * s1 + sa2 * s2;
      out[S + o]     = s1;
      out[2 * S + o] = s2;
    }
  }
}

extern "C" void kernel_launch(void* const* d_in, const int* in_sizes, int n_in,
                              void* d_out, int out_size, void* d_ws, size_t ws_size,
                              hipStream_t stream) {
  const float* item_emb = (const float*)d_in[0];
  const float* prob_emb = (const float*)d_in[1];
  const float* W_cls    = (const float*)d_in[2];
  const float* a1       = (const float*)d_in[3];
  const float* a2       = (const float*)d_in[4];
  const float* Wih      = (const float*)d_in[5];
  const float* Whh      = (const float*)d_in[6];
  const float* bih      = (const float*)d_in[7];
  const float* bhh      = (const float*)d_in[8];
  const float* ln1_g = (const float*)d_in[9];
  const float* ln1_b = (const float*)d_in[10];
  const float* ln2_g = (const float*)d_in[11];
  const float* ln2_b = (const float*)d_in[12];
  const float* ln3_g = (const float*)d_in[13];
  const float* ln3_b = (const float*)d_in[14];
  const float* ln4_g = (const float*)d_in[15];
  const float* ln4_b = (const float*)d_in[16];
  const int* inp_sess = (const int*)d_in[19];
  const int* lengths  = (const int*)d_in[20];
  const int* adj      = (const int*)d_in[21];
  float* out = (float*)d_out;

  // R7's exact layout; hop-1's normalized outputs go to the dead 12.8M-float
  // slot between o2 and gi (the region fp32 tbl/ct used to occupy).
  float* ws = (float*)d_ws;
  const size_t SZ_ROW = (size_t)N_IT * HD;
  float* xn   = ws;
  float* o1   = xn + SZ_ROW;
  float* o2   = o1 + SZ_ROW;
  float* slot = o2 + SZ_ROW;                         // 2*NI*HD floats, free
  float* x1f  = slot;                                // N_IT*HD f32
  unsigned* x1b = (unsigned*)(slot + 6400000);       // N_IT*64 u32 (fits)
  float* gi  = o2 + SZ_ROW + 2 * (size_t)NI * HD;
  float* htb = gi + (size_t)2 * 25600 * G3;

  unsigned* xnb = (unsigned*)gi;                     // dead before gi2 writes gi
  unsigned short* tbf = (unsigned short*)xn;         // written by iv (xn dead after routing1)
  unsigned short* cbf = (unsigned short*)o2;         // written by cls (o2 dead after iv)
  unsigned short* hbf = (unsigned short*)o1;         // written by ln_ht (o1 dead after iv)
  unsigned short* wbf = (unsigned short*)(o2 + 3400000);  // past cbf

  int nb4 = (N_IT + 3) / 4;
  int nb4i = (NI + 3) / 4;

  norm_kernel<<<nb4, 256, 0, stream>>>(item_emb + HD, xn, xnb, N_IT);
  // hop1 + fused normalize -> o1 (raw), x1f/x1b (normalized)
  routing1_kernel<<<nb4, 256, 0, stream>>>(xn, xnb, adj + MNB, o1, x1f, x1b);
  // hop2: R7 kernel verbatim, fed by x1f/x1b
  routing_kernel<<<nb4, 256, 0, stream>>>(x1f, x1b, adj + MNB, o2);
  iv_kernel<<<nb4i, 256, 0, stream>>>(item_emb, o1, o2, ln1_g, ln1_b, tbf);
  cls_kernel<<<nb4i, 256, 0, stream>>>(prob_emb, W_cls, ln3_g, ln3_b, cbf);
  wbf_kernel<<<192, 256, 0, stream>>>(Wih, wbf);
  gi2_kernel<<<3200, 256, 0, stream>>>(tbf, cbf, inp_sess, wbf, gi);
  gru_mfma_kernel<<<64, 512, 0, stream>>>(gi, Whh, bih, bhh, lengths, htb);
  ln_ht_kernel<<<256, 256, 0, stream>>>(htb, ln2_g, ln2_b, ln4_g, ln4_b, hbf);
  scores2_kernel<<<196 * 16, 512, 0, stream>>>(hbf, tbf, cbf, a1, a2, out);
}

// Round 15
// 406.702 us; speedup vs baseline: 1.0488x; 1.0274x over previous
//
#include <hip/hip_runtime.h>
#include <hip/hip_bf16.h>

#define N_IT 49999
#define NI   50000
#define HD   128
#define MNB  16
#define BSZ  512
#define LSEQ 50
#define G3   384

typedef __attribute__((ext_vector_type(8))) short short8;
typedef __attribute__((ext_vector_type(4))) float f32x4;
typedef __attribute__((ext_vector_type(16))) float f32x16;

__device__ __forceinline__ float sigmf(float x) {
  return 1.f / (1.f + __expf(-x));
}
__device__ __forceinline__ float fast_sigm(float x) {
  return __fdividef(1.f, 1.f + __expf(-x));
}
__device__ __forceinline__ float fast_tanh(float x) {
  float e = __expf(-2.f * x);
  return (1.f - e) * __fdividef(1.f, 1.f + e);
}

__device__ __forceinline__ unsigned short f2bf(float f) {
  unsigned u = __float_as_uint(f);
  u += 0x7FFF + ((u >> 16) & 1);
  return (unsigned short)(u >> 16);
}
__device__ __forceinline__ float bf2f(unsigned short v) {
  return __int_as_float(((unsigned)v) << 16);
}

// ---- DPP / swizzle butterfly helpers --------------------------------------
template <int CTRL>
__device__ __forceinline__ float dppadd(float v) {
  int s = __builtin_amdgcn_update_dpp(__float_as_int(v), __float_as_int(v),
                                      CTRL, 0xF, 0xF, false);
  return v + __int_as_float(s);
}
template <int MASK>
__device__ __forceinline__ float swzadd(float v) {
  return v + __int_as_float(__builtin_amdgcn_ds_swizzle(__float_as_int(v), MASK));
}
__device__ __forceinline__ float bp32add(float v) {
  int lane = threadIdx.x & 63;
  return v + __int_as_float(__builtin_amdgcn_ds_bpermute(((lane ^ 32) << 2),
                                                         __float_as_int(v)));
}

__device__ __forceinline__ float wsum(float v) {
  v = dppadd<0xB1>(v);    // i^1
  v = dppadd<0x4E>(v);    // i^2
  v = dppadd<0x141>(v);   // i^7 (row_half_mirror)
  v = dppadd<0x140>(v);   // i^15 (row_mirror)
  v = swzadd<0x401F>(v);  // i^16
  v = bp32add(v);         // i^32
  return v;
}

// ---------------- prelude: norm (item_emb) | cls table | Wih->bf16 ---------
__global__ void prelude_kernel(const float* __restrict__ item_emb,
                               float* __restrict__ xnf, unsigned* __restrict__ xnb,
                               const float* __restrict__ prob,
                               const float* __restrict__ Wc,
                               const float* __restrict__ g3v,
                               const float* __restrict__ b3v,
                               unsigned short* __restrict__ cbf,
                               const float* __restrict__ Wih,
                               unsigned short* __restrict__ wbf) {
  int b = blockIdx.x;
  if (b < 12500) {
    int w = threadIdx.x >> 6, l = threadIdx.x & 63;
    int r = b * 4 + w;
    if (r >= N_IT) return;
    const float* x = item_emb + HD;
    float2 xv = *(const float2*)(x + (size_t)r * HD + 2 * l);
    float sq = wsum(xv.x * xv.x + xv.y * xv.y);
    float inv = 1.f / fmaxf(sqrtf(sq), 1e-12f);
    float a = xv.x * inv, bb = xv.y * inv;
    *(float2*)(xnf + (size_t)r * HD + 2 * l) = make_float2(a, bb);
    xnb[(size_t)r * 64 + l] = (unsigned)f2bf(a) | ((unsigned)f2bf(bb) << 16);
  } else if (b < 25000) {
    int w = threadIdx.x >> 6, l = threadIdx.x & 63;
    int r = (b - 12500) * 4 + w;
    if (r >= NI) return;
    float p[10];
#pragma unroll
    for (int k = 0; k < 10; ++k) p[k] = prob[(size_t)r * 10 + k];
    float a = 0.f, bb = 0.f;
#pragma unroll
    for (int k = 0; k < 10; ++k) {
      a += p[k] * Wc[l * 10 + k];
      bb += p[k] * Wc[(l + 64) * 10 + k];
    }
    float mu = wsum(a + bb) * (1.f / HD);
    float v  = wsum(a * a + bb * bb) * (1.f / HD) - mu * mu;
    float rs = rsqrtf(v + 1e-5f);
    float va = (a - mu) * rs * g3v[l] + b3v[l];
    float vb = (bb - mu) * rs * g3v[l + 64] + b3v[l + 64];
    cbf[(size_t)r * HD + l]      = f2bf(va);
    cbf[(size_t)r * HD + l + 64] = f2bf(vb);
  } else {
    int i = (b - 25000) * 256 + threadIdx.x;
    if (i < 3 * HD * HD) wbf[i] = f2bf(Wih[i]);
  }
}

// ---------------- routing hop1 + fused normalize epilogue (R12 verbatim) ---
__global__ __launch_bounds__(256) void routing1_kernel(
    const float* __restrict__ xn, const unsigned* __restrict__ xnb,
    const int* __restrict__ adj, float* __restrict__ out,
    float* __restrict__ onf, unsigned* __restrict__ onb) {
  __shared__ char zsh[4][4096];
  int tid = threadIdx.x;
  int w = tid >> 6, lane = tid & 63;
  int n = blockIdx.x * 4 + w;
  if (n >= N_IT) return;
  int m = lane & 15, quad = lane >> 4;
  const unsigned short* xb16 = (const unsigned short*)xnb;

  int idx = adj[n * MNB + m] - 1;
  const unsigned short* zrow = xb16 + (size_t)idx * HD;
  const unsigned short* xrow = xb16 + (size_t)n * HD;
  short8 zf[4], xf[4];
#pragma unroll
  for (int kk = 0; kk < 4; ++kk) {
    zf[kk] = *(const short8*)(zrow + kk * 32 + quad * 8);
    xf[kk] = *(const short8*)(xrow + kk * 32 + quad * 8);
  }
  f32x4 Gf = {0.f, 0.f, 0.f, 0.f}, Bv = {0.f, 0.f, 0.f, 0.f};
#pragma unroll
  for (int kk = 0; kk < 4; ++kk) {
    Gf = __builtin_amdgcn_mfma_f32_16x16x32_bf16(zf[kk], zf[kk], Gf, 0, 0, 0);
    Bv = __builtin_amdgcn_mfma_f32_16x16x32_bf16(zf[kk], xf[kk], Bv, 0, 0, 0);
  }
  char* zb = zsh[w] + m * 256;
#pragma unroll
  for (int kk = 0; kk < 4; ++kk)
    *(short8*)(zb + ((kk * 64 + quad * 16) ^ ((m & 7) << 4))) = zf[kk];

  float pc0 = 0.0625f, pc1 = 0.0625f, pc2 = 0.0625f, pc3 = 0.0625f;
  int msel = lane & 3;
  int cjaddr = (((lane >> 2) & 3) << 4 | (lane & 3)) << 2;

#pragma unroll
  for (int it = 0; it < 3; ++it) {
    float selv = (msel == 0) ? pc0 : (msel == 1) ? pc1 : (msel == 2) ? pc2 : pc3;
    float cj = __int_as_float(
        __builtin_amdgcn_ds_bpermute(cjaddr, __float_as_int(selv)));
    float g0 = Gf[0] * cj, g1 = Gf[1] * cj, g2 = Gf[2] * cj, g3 = Gf[3] * cj;
    g0 = dppadd<0xB1>(g0); g1 = dppadd<0xB1>(g1); g2 = dppadd<0xB1>(g2); g3 = dppadd<0xB1>(g3);
    g0 = dppadd<0x4E>(g0); g1 = dppadd<0x4E>(g1); g2 = dppadd<0x4E>(g2); g3 = dppadd<0x4E>(g3);
    g0 = swzadd<0x101F>(g0); g1 = swzadd<0x101F>(g1); g2 = swzadd<0x101F>(g2); g3 = swzadd<0x101F>(g3);
    g0 = swzadd<0x201F>(g0); g1 = swzadd<0x201F>(g1); g2 = swzadd<0x201F>(g2); g3 = swzadd<0x201F>(g3);
    float t1 = pc0 * g0 + pc1 * g1 + pc2 * g2 + pc3 * g3;
    float t2 = pc0 * Bv[0] + pc1 * Bv[1] + pc2 * Bv[2] + pc3 * Bv[3];
    t1 = swzadd<0x401F>(t1); t1 = bp32add(t1);
    t2 = swzadd<0x401F>(t2); t2 = bp32add(t2);
    float sq = fmaxf(1.f + 2.f * t2 + t1, 0.f);
    float s = (sq / (sq + 1.f)) / fmaxf(sqrtf(sq), 1e-12f);
    float e0 = __expf(s * (Bv[0] + g0));
    float e1 = __expf(s * (Bv[1] + g1));
    float e2 = __expf(s * (Bv[2] + g2));
    float e3 = __expf(s * (Bv[3] + g3));
    float se = e0 + e1 + e2 + e3;
    se = swzadd<0x401F>(se); se = bp32add(se);
    float inv = __fdividef(1.f, se);
    pc0 = e0 * inv; pc1 = e1 * inv; pc2 = e2 * inv; pc3 = e3 * inv;
  }
  float selv = (msel == 0) ? pc0 : (msel == 1) ? pc1 : (msel == 2) ? pc2 : pc3;
  float2 xv = *(const float2*)(xn + (size_t)n * HD + 2 * lane);
  float u0 = xv.x, u1 = xv.y;
#pragma unroll
  for (int mm = 0; mm < MNB; ++mm) {
    int srcl = ((((mm >> 2) << 4) | (mm & 3)) << 2);
    float pm = __int_as_float(
        __builtin_amdgcn_ds_bpermute(srcl, __float_as_int(selv)));
    unsigned zv = *(const unsigned*)(zsh[w] + mm * 256 +
                                     ((4 * lane) ^ ((mm & 7) << 4)));
    float z0 = __int_as_float((zv & 0xFFFFu) << 16);
    float z1 = __int_as_float((zv >> 16) << 16);
    u0 += z0 * pm;
    u1 += z1 * pm;
  }
  *(float2*)(out + (size_t)n * HD + 2 * lane) = make_float2(u0, u1);
  float nsq = wsum(u0 * u0 + u1 * u1);
  float ninv = 1.f / fmaxf(sqrtf(nsq), 1e-12f);
  float na = u0 * ninv, nb = u1 * ninv;
  *(float2*)(onf + (size_t)n * HD + 2 * lane) = make_float2(na, nb);
  onb[(size_t)n * 64 + lane] = (unsigned)f2bf(na) | ((unsigned)f2bf(nb) << 16);
}

// ---------------- routing v3 (hop2): R7/R12 verbatim -----------------------
__global__ __launch_bounds__(256) void routing_kernel(
    const float* __restrict__ xn, const unsigned* __restrict__ xnb,
    const int* __restrict__ adj, float* __restrict__ out) {
  __shared__ char zsh[4][4096];
  int tid = threadIdx.x;
  int w = tid >> 6, lane = tid & 63;
  int n = blockIdx.x * 4 + w;
  if (n >= N_IT) return;
  int m = lane & 15, quad = lane >> 4;
  const unsigned short* xb16 = (const unsigned short*)xnb;

  int idx = adj[n * MNB + m] - 1;
  const unsigned short* zrow = xb16 + (size_t)idx * HD;
  const unsigned short* xrow = xb16 + (size_t)n * HD;
  short8 zf[4], xf[4];
#pragma unroll
  for (int kk = 0; kk < 4; ++kk) {
    zf[kk] = *(const short8*)(zrow + kk * 32 + quad * 8);
    xf[kk] = *(const short8*)(xrow + kk * 32 + quad * 8);
  }
  f32x4 Gf = {0.f, 0.f, 0.f, 0.f}, Bv = {0.f, 0.f, 0.f, 0.f};
#pragma unroll
  for (int kk = 0; kk < 4; ++kk) {
    Gf = __builtin_amdgcn_mfma_f32_16x16x32_bf16(zf[kk], zf[kk], Gf, 0, 0, 0);
    Bv = __builtin_amdgcn_mfma_f32_16x16x32_bf16(zf[kk], xf[kk], Bv, 0, 0, 0);
  }
  char* zb = zsh[w] + m * 256;
#pragma unroll
  for (int kk = 0; kk < 4; ++kk)
    *(short8*)(zb + ((kk * 64 + quad * 16) ^ ((m & 7) << 4))) = zf[kk];

  float pc0 = 0.0625f, pc1 = 0.0625f, pc2 = 0.0625f, pc3 = 0.0625f;
  int msel = lane & 3;
  int cjaddr = (((lane >> 2) & 3) << 4 | (lane & 3)) << 2;

#pragma unroll
  for (int it = 0; it < 3; ++it) {
    float selv = (msel == 0) ? pc0 : (msel == 1) ? pc1 : (msel == 2) ? pc2 : pc3;
    float cj = __int_as_float(
        __builtin_amdgcn_ds_bpermute(cjaddr, __float_as_int(selv)));
    float g0 = Gf[0] * cj, g1 = Gf[1] * cj, g2 = Gf[2] * cj, g3 = Gf[3] * cj;
    g0 = dppadd<0xB1>(g0); g1 = dppadd<0xB1>(g1); g2 = dppadd<0xB1>(g2); g3 = dppadd<0xB1>(g3);
    g0 = dppadd<0x4E>(g0); g1 = dppadd<0x4E>(g1); g2 = dppadd<0x4E>(g2); g3 = dppadd<0x4E>(g3);
    g0 = swzadd<0x101F>(g0); g1 = swzadd<0x101F>(g1); g2 = swzadd<0x101F>(g2); g3 = swzadd<0x101F>(g3);
    g0 = swzadd<0x201F>(g0); g1 = swzadd<0x201F>(g1); g2 = swzadd<0x201F>(g2); g3 = swzadd<0x201F>(g3);
    float t1 = pc0 * g0 + pc1 * g1 + pc2 * g2 + pc3 * g3;
    float t2 = pc0 * Bv[0] + pc1 * Bv[1] + pc2 * Bv[2] + pc3 * Bv[3];
    t1 = swzadd<0x401F>(t1); t1 = bp32add(t1);
    t2 = swzadd<0x401F>(t2); t2 = bp32add(t2);
    float sq = fmaxf(1.f + 2.f * t2 + t1, 0.f);
    float s = (sq / (sq + 1.f)) / fmaxf(sqrtf(sq), 1e-12f);
    float e0 = __expf(s * (Bv[0] + g0));
    float e1 = __expf(s * (Bv[1] + g1));
    float e2 = __expf(s * (Bv[2] + g2));
    float e3 = __expf(s * (Bv[3] + g3));
    float se = e0 + e1 + e2 + e3;
    se = swzadd<0x401F>(se); se = bp32add(se);
    float inv = __fdividef(1.f, se);
    pc0 = e0 * inv; pc1 = e1 * inv; pc2 = e2 * inv; pc3 = e3 * inv;
  }
  float selv = (msel == 0) ? pc0 : (msel == 1) ? pc1 : (msel == 2) ? pc2 : pc3;
  float2 xv = *(const float2*)(xn + (size_t)n * HD + 2 * lane);
  float u0 = xv.x, u1 = xv.y;
#pragma unroll
  for (int mm = 0; mm < MNB; ++mm) {
    int srcl = ((((mm >> 2) << 4) | (mm & 3)) << 2);
    float pm = __int_as_float(
        __builtin_amdgcn_ds_bpermute(srcl, __float_as_int(selv)));
    unsigned zv = *(const unsigned*)(zsh[w] + mm * 256 +
                                     ((4 * lane) ^ ((mm & 7) << 4)));
    float z0 = __int_as_float((zv & 0xFFFFu) << 16);
    float z1 = __int_as_float((zv >> 16) << 16);
    u0 += z0 * pm;
    u1 += z1 * pm;
  }
  *(float2*)(out + (size_t)n * HD + 2 * lane) = make_float2(u0, u1);
}

// ---------------- iv table (bf16 only): row0=0; rows 1..: LN1(x0+o1+o2) ----
__global__ void iv_kernel(const float* __restrict__ item_emb,
                          const float* __restrict__ o1, const float* __restrict__ o2,
                          const float* __restrict__ g, const float* __restrict__ bb,
                          unsigned short* __restrict__ tbf) {
  int w = threadIdx.x >> 6, l = threadIdx.x & 63;
  int r = blockIdx.x * 4 + w;
  if (r >= NI) return;
  if (r == 0) {
    tbf[l] = 0; tbf[l + 64] = 0;
    return;
  }
  size_t pr = (size_t)(r - 1) * HD;
  float a = item_emb[(size_t)r * HD + l]      + o1[pr + l]      + o2[pr + l];
  float b = item_emb[(size_t)r * HD + l + 64] + o1[pr + l + 64] + o2[pr + l + 64];
  float mu = wsum(a + b) * (1.f / HD);
  float v  = wsum(a * a + b * b) * (1.f / HD) - mu * mu;
  float rs = rsqrtf(v + 1e-5f);
  float va = (a - mu) * rs * g[l] + bb[l];
  float vb = (b - mu) * rs * g[l + 64] + bb[l + 64];
  tbf[(size_t)r * HD + l]      = f2bf(va);
  tbf[(size_t)r * HD + l + 64] = f2bf(vb);
}

// ---------------- gi via MFMA, bf16 out ------------------------------------
__global__ __launch_bounds__(256) void gi2_kernel(
    const unsigned short* __restrict__ tbf, const unsigned short* __restrict__ cbf,
    const int* __restrict__ sess, const unsigned short* __restrict__ wbf,
    unsigned short* __restrict__ gib) {
  __shared__ int sidx[16];
  int tid = threadIdx.x;
  int row0 = blockIdx.x * 16;
  if (tid < 16) sidx[tid] = sess[(row0 + tid) % 25600];
  __syncthreads();
  const unsigned short* src = (row0 < 25600) ? tbf : cbf;
  int w = tid >> 6, lane = tid & 63;
  int rloc = lane & 15, quad = lane >> 4;
  int arow = sidx[rloc];
  int ko = quad * 8;
  short8 A[4];
#pragma unroll
  for (int kk = 0; kk < 4; ++kk)
    A[kk] = *(const short8*)(src + (size_t)arow * HD + kk * 32 + ko);
  unsigned short* gout = gib + (size_t)row0 * G3;
#pragma unroll
  for (int s = 0; s < 6; ++s) {
    int jt = w * 6 + s;
    int j = jt * 16 + rloc;
    f32x4 acc = {0.f, 0.f, 0.f, 0.f};
#pragma unroll
    for (int kk = 0; kk < 4; ++kk) {
      short8 B = *(const short8*)(wbf + (size_t)j * HD + kk * 32 + ko);
      acc = __builtin_amdgcn_mfma_f32_16x16x32_bf16(A[kk], B, acc, 0, 0, 0);
    }
#pragma unroll
    for (int q = 0; q < 4; ++q)
      gout[(size_t)(quad * 4 + q) * G3 + jt * 16 + rloc] = f2bf(acc[q]);
  }
}

// ---------------- GRU recurrence via MFMA (gi bf16) ------------------------
__global__ __launch_bounds__(512) void gru_mfma_kernel(
    const unsigned short* __restrict__ gi_all, const float* __restrict__ Whh,
    const float* __restrict__ bih, const float* __restrict__ bhh,
    const int* __restrict__ lengths, float* __restrict__ ht_raw) {
  __shared__ unsigned short hlds[2][16 * HD];  // 8 KB
  int tid = threadIdx.x;
  int lane = tid & 63;
  int w = tid >> 6;
  int p = blockIdx.x >> 5;
  int r0 = (blockIdx.x & 31) * 16;
  int cN = lane & 15;
  int quad = lane >> 4;
  int d = w * 16 + cN;

  {
    int* hz = (int*)hlds;
    for (int i = tid; i < 2 * 16 * HD / 2; i += 512) hz[i] = 0;
  }

  short8 Br[4], Bz[4], Bn[4];
#pragma unroll
  for (int kk = 0; kk < 4; ++kk) {
    int kbase = quad * 8 + kk * 32;
    const float* wr_ = Whh + (size_t)d * HD + kbase;
    const float* wz_ = Whh + (size_t)(128 + d) * HD + kbase;
    const float* wn_ = Whh + (size_t)(256 + d) * HD + kbase;
    float4 r0v = *(const float4*)wr_, r1v = *(const float4*)(wr_ + 4);
    float4 z0v = *(const float4*)wz_, z1v = *(const float4*)(wz_ + 4);
    float4 n0v = *(const float4*)wn_, n1v = *(const float4*)(wn_ + 4);
    short8 br, bz, bn;
    br[0]=(short)f2bf(r0v.x); br[1]=(short)f2bf(r0v.y); br[2]=(short)f2bf(r0v.z); br[3]=(short)f2bf(r0v.w);
    br[4]=(short)f2bf(r1v.x); br[5]=(short)f2bf(r1v.y); br[6]=(short)f2bf(r1v.z); br[7]=(short)f2bf(r1v.w);
    bz[0]=(short)f2bf(z0v.x); bz[1]=(short)f2bf(z0v.y); bz[2]=(short)f2bf(z0v.z); bz[3]=(short)f2bf(z0v.w);
    bz[4]=(short)f2bf(z1v.x); bz[5]=(short)f2bf(z1v.y); bz[6]=(short)f2bf(z1v.z); bz[7]=(short)f2bf(z1v.w);
    bn[0]=(short)f2bf(n0v.x); bn[1]=(short)f2bf(n0v.y); bn[2]=(short)f2bf(n0v.z); bn[3]=(short)f2bf(n0v.w);
    bn[4]=(short)f2bf(n1v.x); bn[5]=(short)f2bf(n1v.y); bn[6]=(short)f2bf(n1v.z); bn[7]=(short)f2bf(n1v.w);
    Br[kk] = br; Bz[kk] = bz; Bn[kk] = bn;
  }
  float cr = bhh[d] + bih[d];
  float cz = bhh[128 + d] + bih[128 + d];
  float bhn = bhh[256 + d], bin = bih[256 + d];

  int lens4[4];
  float hold[4];
  const unsigned short* gptr[4];
#pragma unroll
  for (int gq = 0; gq < 4; ++gq) {
    int lr = quad * 4 + gq;
    lens4[gq] = lengths[r0 + lr] - 1;
    hold[gq] = 0.f;
    gptr[gq] = gi_all + ((size_t)p * 25600 + (size_t)(r0 + lr) * LSEQ) * G3 + d;
  }

  int aoff[4];
#pragma unroll
  for (int kk = 0; kk < 4; ++kk)
    aoff[kk] = cN * 256 + (((quad * 8 + kk * 32) * 2) ^ ((cN & 7) << 4));
  int woff[4];
#pragma unroll
  for (int gq = 0; gq < 4; ++gq) {
    int lr = quad * 4 + gq;
    woff[gq] = lr * 256 + ((2 * d) ^ ((lr & 7) << 4));
  }

  float giaR[4], giaZ[4], giaN[4];
#pragma unroll
  for (int gq = 0; gq < 4; ++gq) {
    giaR[gq] = bf2f(gptr[gq][0]);
    giaZ[gq] = bf2f(gptr[gq][HD]);
    giaN[gq] = bf2f(gptr[gq][2 * HD]);
  }
  __syncthreads();

  for (int t = 0; t < LSEQ; ++t) {
    float gbR[4], gbZ[4], gbN[4];
#pragma unroll
    for (int gq = 0; gq < 4; ++gq) {
      const unsigned short* gp = gptr[gq] + (size_t)(t + 1) * G3;
      gbR[gq] = bf2f(gp[0]); gbZ[gq] = bf2f(gp[HD]); gbN[gq] = bf2f(gp[2 * HD]);
    }
    const char* hb = (const char*)hlds[t & 1];
    f32x4 accR = {0.f, 0.f, 0.f, 0.f};
    f32x4 accZ = {0.f, 0.f, 0.f, 0.f};
    f32x4 accN = {0.f, 0.f, 0.f, 0.f};
#pragma unroll
    for (int kk = 0; kk < 4; ++kk) {
      short8 A = *(const short8*)(hb + aoff[kk]);
      accR = __builtin_amdgcn_mfma_f32_16x16x32_bf16(A, Br[kk], accR, 0, 0, 0);
      accZ = __builtin_amdgcn_mfma_f32_16x16x32_bf16(A, Bz[kk], accZ, 0, 0, 0);
      accN = __builtin_amdgcn_mfma_f32_16x16x32_bf16(A, Bn[kk], accN, 0, 0, 0);
    }
    char* hw = (char*)hlds[(t + 1) & 1];
#pragma unroll
    for (int gq = 0; gq < 4; ++gq) {
      float rg = fast_sigm(giaR[gq] + accR[gq] + cr);
      float zg = fast_sigm(giaZ[gq] + accZ[gq] + cz);
      float ng = fast_tanh(giaN[gq] + bin + rg * (accN[gq] + bhn));
      float hnew = (1.f - zg) * ng + zg * hold[gq];
      hold[gq] = hnew;
      *(unsigned short*)(hw + woff[gq]) = f2bf(hnew);
      if (t == lens4[gq])
        ht_raw[((size_t)p * BSZ + r0 + quad * 4 + gq) * HD + d] = hnew;
    }
    __syncthreads();
#pragma unroll
    for (int gq = 0; gq < 4; ++gq) {
      giaR[gq] = gbR[gq]; giaZ[gq] = gbZ[gq]; giaN[gq] = gbN[gq];
    }
  }
}

// ---------------- layernorm ht + bf16 copy ---------------------------------
__global__ void ln_ht_kernel(const float* __restrict__ ht,
                             const float* __restrict__ g2, const float* __restrict__ b2,
                             const float* __restrict__ g4, const float* __restrict__ b4,
                             unsigned short* __restrict__ hbf) {
  int w = threadIdx.x >> 6, l = threadIdx.x & 63;
  int r = blockIdx.x * 4 + w;
  if (r >= 2 * BSZ) return;
  const float* g = (r < BSZ) ? g2 : g4;
  const float* bb = (r < BSZ) ? b2 : b4;
  float a = ht[(size_t)r * HD + l];
  float b = ht[(size_t)r * HD + l + 64];
  float mu = wsum(a + b) * (1.f / HD);
  float v  = wsum(a * a + b * b) * (1.f / HD) - mu * mu;
  float rs = rsqrtf(v + 1e-5f);
  float va = (a - mu) * rs * g[l] + bb[l];
  float vb = (b - mu) * rs * g[l + 64] + bb[l + 64];
  hbf[(size_t)r * HD + l]      = f2bf(va);
  hbf[(size_t)r * HD + l + 64] = f2bf(vb);
}

// ---------------- scores: 32x32x16 MFMA + LDS-staged contiguous stores -----
#define JW 256
__global__ __launch_bounds__(512) void scores2_kernel(
    const unsigned short* __restrict__ hbf,
    const unsigned short* __restrict__ tbf,
    const unsigned short* __restrict__ cbf,
    const float* __restrict__ a1p, const float* __restrict__ a2p,
    float* __restrict__ out) {
  __shared__ float s1l[32 * JW];
  __shared__ float s2l[32 * JW];
  int tid = threadIdx.x;
  int w = tid >> 6, lane = tid & 63;
  int strip = blockIdx.x >> 4;
  int r0b = (blockIdx.x & 15) * 32;
  int j0 = strip * JW;
  int jc = j0 + w * 32 + (lane & 31);
  int jl = (jc < N_IT) ? jc : (N_IT - 1);
  int koA = (lane >> 5) * 8;

  f32x16 acc1 = {0.f}, acc2 = {0.f};
  const unsigned short* h1p = hbf + (size_t)(r0b + (lane & 31)) * HD + koA;
  const unsigned short* h2p = h1p + (size_t)BSZ * HD;
  const unsigned short* b1p = tbf + (size_t)(jl + 1) * HD + koA;
  const unsigned short* b2p = cbf + (size_t)(jl + 1) * HD + koA;
#pragma unroll
  for (int kk = 0; kk < 8; ++kk) {
    short8 A1 = *(const short8*)(h1p + kk * 16);
    short8 A2 = *(const short8*)(h2p + kk * 16);
    short8 B1 = *(const short8*)(b1p + kk * 16);
    short8 B2 = *(const short8*)(b2p + kk * 16);
    acc1 = __builtin_amdgcn_mfma_f32_32x32x16_bf16(A1, B1, acc1, 0, 0, 0);
    acc2 = __builtin_amdgcn_mfma_f32_32x32x16_bf16(A2, B2, acc2, 0, 0, 0);
  }
  int colb = w * 32 + (lane & 31);
#pragma unroll
  for (int q = 0; q < 16; ++q) {
    int row = (q & 3) + 8 * (q >> 2) + 4 * (lane >> 5);
    s1l[row * JW + colb] = acc1[q];
    s2l[row * JW + colb] = acc2[q];
  }
  __syncthreads();

  float sa1 = sigmf(a1p[0]);
  float sa2 = sigmf(a2p[0]);
  const size_t S = (size_t)BSZ * N_IT;
#pragma unroll
  for (int pss = 0; pss < 16; ++pss) {
    int idx = pss * 512 + tid;
    int row = idx >> 8;
    int jlc = idx & 255;
    int jg = j0 + jlc;
    if (jg < N_IT) {
      float s1 = s1l[idx];
      float s2 = s2l[idx];
      size_t o = (size_t)(r0b + row) * N_IT + jg;
      out[o]         = sa1 * s1 + sa2 * s2;
      out[S + o]     = s1;
      out[2 * S + o] = s2;
    }
  }
}

extern "C" void kernel_launch(void* const* d_in, const int* in_sizes, int n_in,
                              void* d_out, int out_size, void* d_ws, size_t ws_size,
                              hipStream_t stream) {
  const float* item_emb = (const float*)d_in[0];
  const float* prob_emb = (const float*)d_in[1];
  const float* W_cls    = (const float*)d_in[2];
  const float* a1       = (const float*)d_in[3];
  const float* a2       = (const float*)d_in[4];
  const float* Wih      = (const float*)d_in[5];
  const float* Whh      = (const float*)d_in[6];
  const float* bih      = (const float*)d_in[7];
  const float* bhh      = (const float*)d_in[8];
  const float* ln1_g = (const float*)d_in[9];
  const float* ln1_b = (const float*)d_in[10];
  const float* ln2_g = (const float*)d_in[11];
  const float* ln2_b = (const float*)d_in[12];
  const float* ln3_g = (const float*)d_in[13];
  const float* ln3_b = (const float*)d_in[14];
  const float* ln4_g = (const float*)d_in[15];
  const float* ln4_b = (const float*)d_in[16];
  const int* inp_sess = (const int*)d_in[19];
  const int* lengths  = (const int*)d_in[20];
  const int* adj      = (const int*)d_in[21];
  float* out = (float*)d_out;

  // Layout (lifetime-audited; prelude runs FIRST so cbf/wbf must NOT alias o2):
  //  xn | o1 | o2 | slot{x1f, x1b, cbf} | gi{xnb->gib, wbf@+10M} | htb
  float* ws = (float*)d_ws;
  const size_t SZ_ROW = (size_t)N_IT * HD;
  float* xn   = ws;
  float* o1   = xn + SZ_ROW;
  float* o2   = o1 + SZ_ROW;
  float* slot = o2 + SZ_ROW;                          // 2*NI*HD = 12.8M floats
  float* x1f  = slot;                                 // 6.4M f32
  unsigned* x1b = (unsigned*)(slot + 6400000);        // 3.2M u32
  unsigned short* cbf = (unsigned short*)(slot + 9600000);  // 6.4M bf16 (ends at slot+12.8M)
  float* gi  = slot + 2 * (size_t)NI * HD;            // 19.66M floats region
  float* htb = gi + (size_t)2 * 25600 * G3;

  unsigned* xnb = (unsigned*)gi;                      // 12.8 MB; dead before gib written
  unsigned short* gib = (unsigned short*)gi;          // bf16 gi: bytes [0, 39.3MB)
  unsigned short* wbf = (unsigned short*)(gi + 10000000);  // byte 40MB: past gib+overread
  unsigned short* tbf = (unsigned short*)xn;          // written by iv (xn dead after routing1)
  unsigned short* hbf = (unsigned short*)o1;          // written by ln_ht (o1 dead after iv)

  int nb4 = (N_IT + 3) / 4;
  int nb4i = (NI + 3) / 4;

  prelude_kernel<<<25192, 256, 0, stream>>>(item_emb, xn, xnb,
                                            prob_emb, W_cls, ln3_g, ln3_b, cbf,
                                            Wih, wbf);
  routing1_kernel<<<nb4, 256, 0, stream>>>(xn, xnb, adj + MNB, o1, x1f, x1b);
  routing_kernel<<<nb4, 256, 0, stream>>>(x1f, x1b, adj + MNB, o2);
  iv_kernel<<<nb4i, 256, 0, stream>>>(item_emb, o1, o2, ln1_g, ln1_b, tbf);
  gi2_kernel<<<3200, 256, 0, stream>>>(tbf, cbf, inp_sess, wbf, gib);
  gru_mfma_kernel<<<64, 512, 0, stream>>>(gib, Whh, bih, bhh, lengths, htb);
  ln_ht_kernel<<<256, 256, 0, stream>>>(htb, ln2_g, ln2_b, ln4_g, ln4_b, hbf);
  scores2_kernel<<<196 * 16, 512, 0, stream>>>(hbf, tbf, cbf, a1, a2, out);
}

// Round 16
// 406.442 us; speedup vs baseline: 1.0495x; 1.0006x over previous
//
#include <hip/hip_runtime.h>
#include <hip/hip_bf16.h>

#define N_IT 49999
#define NI   50000
#define HD   128
#define MNB  16
#define BSZ  512
#define LSEQ 50
#define G3   384

typedef __attribute__((ext_vector_type(8))) short short8;
typedef __attribute__((ext_vector_type(4))) float f32x4;
typedef __attribute__((ext_vector_type(16))) float f32x16;
typedef __attribute__((ext_vector_type(4))) int int4v;

__device__ __forceinline__ float sigmf(float x) {
  return 1.f / (1.f + __expf(-x));
}
__device__ __forceinline__ float fast_sigm(float x) {
  return __fdividef(1.f, 1.f + __expf(-x));
}
__device__ __forceinline__ float fast_tanh(float x) {
  float e = __expf(-2.f * x);
  return (1.f - e) * __fdividef(1.f, 1.f + e);
}

__device__ __forceinline__ unsigned short f2bf(float f) {
  unsigned u = __float_as_uint(f);
  u += 0x7FFF + ((u >> 16) & 1);
  return (unsigned short)(u >> 16);
}
__device__ __forceinline__ float bf2f(unsigned short v) {
  return __int_as_float(((unsigned)v) << 16);
}

// ---- DPP / swizzle butterfly helpers --------------------------------------
template <int CTRL>
__device__ __forceinline__ float dppadd(float v) {
  int s = __builtin_amdgcn_update_dpp(__float_as_int(v), __float_as_int(v),
                                      CTRL, 0xF, 0xF, false);
  return v + __int_as_float(s);
}
template <int MASK>
__device__ __forceinline__ float swzadd(float v) {
  return v + __int_as_float(__builtin_amdgcn_ds_swizzle(__float_as_int(v), MASK));
}
__device__ __forceinline__ float bp32add(float v) {
  int lane = threadIdx.x & 63;
  return v + __int_as_float(__builtin_amdgcn_ds_bpermute(((lane ^ 32) << 2),
                                                         __float_as_int(v)));
}

__device__ __forceinline__ float wsum(float v) {
  v = dppadd<0xB1>(v);    // i^1
  v = dppadd<0x4E>(v);    // i^2
  v = dppadd<0x141>(v);   // i^7 (row_half_mirror)
  v = dppadd<0x140>(v);   // i^15 (row_mirror)
  v = swzadd<0x401F>(v);  // i^16
  v = bp32add(v);         // i^32
  return v;
}

// ---------------- prelude: norm (item_emb) | cls table | Wih->bf16 ---------
__global__ void prelude_kernel(const float* __restrict__ item_emb,
                               float* __restrict__ xnf, unsigned* __restrict__ xnb,
                               const float* __restrict__ prob,
                               const float* __restrict__ Wc,
                               const float* __restrict__ g3v,
                               const float* __restrict__ b3v,
                               unsigned short* __restrict__ cbf,
                               const float* __restrict__ Wih,
                               unsigned short* __restrict__ wbf) {
  int b = blockIdx.x;
  if (b < 12500) {
    int w = threadIdx.x >> 6, l = threadIdx.x & 63;
    int r = b * 4 + w;
    if (r >= N_IT) return;
    const float* x = item_emb + HD;
    float2 xv = *(const float2*)(x + (size_t)r * HD + 2 * l);
    float sq = wsum(xv.x * xv.x + xv.y * xv.y);
    float inv = 1.f / fmaxf(sqrtf(sq), 1e-12f);
    float a = xv.x * inv, bb = xv.y * inv;
    *(float2*)(xnf + (size_t)r * HD + 2 * l) = make_float2(a, bb);
    xnb[(size_t)r * 64 + l] = (unsigned)f2bf(a) | ((unsigned)f2bf(bb) << 16);
  } else if (b < 25000) {
    int w = threadIdx.x >> 6, l = threadIdx.x & 63;
    int r = (b - 12500) * 4 + w;
    if (r >= NI) return;
    float p[10];
#pragma unroll
    for (int k = 0; k < 10; ++k) p[k] = prob[(size_t)r * 10 + k];
    float a = 0.f, bb = 0.f;
#pragma unroll
    for (int k = 0; k < 10; ++k) {
      a += p[k] * Wc[l * 10 + k];
      bb += p[k] * Wc[(l + 64) * 10 + k];
    }
    float mu = wsum(a + bb) * (1.f / HD);
    float v  = wsum(a * a + bb * bb) * (1.f / HD) - mu * mu;
    float rs = rsqrtf(v + 1e-5f);
    float va = (a - mu) * rs * g3v[l] + b3v[l];
    float vb = (bb - mu) * rs * g3v[l + 64] + b3v[l + 64];
    cbf[(size_t)r * HD + l]      = f2bf(va);
    cbf[(size_t)r * HD + l + 64] = f2bf(vb);
  } else {
    int i = (b - 25000) * 256 + threadIdx.x;
    if (i < 3 * HD * HD) wbf[i] = f2bf(Wih[i]);
  }
}

// ---------------- routing hop1 + fused normalize epilogue ------------------
__global__ __launch_bounds__(256) void routing1_kernel(
    const float* __restrict__ xn, const unsigned* __restrict__ xnb,
    const int* __restrict__ adj, float* __restrict__ out,
    float* __restrict__ onf, unsigned* __restrict__ onb) {
  __shared__ char zsh[4][4096];
  int tid = threadIdx.x;
  int w = tid >> 6, lane = tid & 63;
  int n = blockIdx.x * 4 + w;
  if (n >= N_IT) return;
  int m = lane & 15, quad = lane >> 4;
  const unsigned short* xb16 = (const unsigned short*)xnb;

  int idx = adj[n * MNB + m] - 1;
  const unsigned short* zrow = xb16 + (size_t)idx * HD;
  const unsigned short* xrow = xb16 + (size_t)n * HD;
  short8 zf[4], xf[4];
#pragma unroll
  for (int kk = 0; kk < 4; ++kk) {
    zf[kk] = *(const short8*)(zrow + kk * 32 + quad * 8);
    xf[kk] = *(const short8*)(xrow + kk * 32 + quad * 8);
  }
  f32x4 Gf = {0.f, 0.f, 0.f, 0.f}, Bv = {0.f, 0.f, 0.f, 0.f};
#pragma unroll
  for (int kk = 0; kk < 4; ++kk) {
    Gf = __builtin_amdgcn_mfma_f32_16x16x32_bf16(zf[kk], zf[kk], Gf, 0, 0, 0);
    Bv = __builtin_amdgcn_mfma_f32_16x16x32_bf16(zf[kk], xf[kk], Bv, 0, 0, 0);
  }
  char* zb = zsh[w] + m * 256;
#pragma unroll
  for (int kk = 0; kk < 4; ++kk)
    *(short8*)(zb + ((kk * 64 + quad * 16) ^ ((m & 7) << 4))) = zf[kk];

  float pc0 = 0.0625f, pc1 = 0.0625f, pc2 = 0.0625f, pc3 = 0.0625f;
  int msel = lane & 3;
  int cjaddr = (((lane >> 2) & 3) << 4 | (lane & 3)) << 2;

#pragma unroll
  for (int it = 0; it < 3; ++it) {
    float selv = (msel == 0) ? pc0 : (msel == 1) ? pc1 : (msel == 2) ? pc2 : pc3;
    float cj = __int_as_float(
        __builtin_amdgcn_ds_bpermute(cjaddr, __float_as_int(selv)));
    float g0 = Gf[0] * cj, g1 = Gf[1] * cj, g2 = Gf[2] * cj, g3 = Gf[3] * cj;
    g0 = dppadd<0xB1>(g0); g1 = dppadd<0xB1>(g1); g2 = dppadd<0xB1>(g2); g3 = dppadd<0xB1>(g3);
    g0 = dppadd<0x4E>(g0); g1 = dppadd<0x4E>(g1); g2 = dppadd<0x4E>(g2); g3 = dppadd<0x4E>(g3);
    g0 = swzadd<0x101F>(g0); g1 = swzadd<0x101F>(g1); g2 = swzadd<0x101F>(g2); g3 = swzadd<0x101F>(g3);
    g0 = swzadd<0x201F>(g0); g1 = swzadd<0x201F>(g1); g2 = swzadd<0x201F>(g2); g3 = swzadd<0x201F>(g3);
    float t1 = pc0 * g0 + pc1 * g1 + pc2 * g2 + pc3 * g3;
    float t2 = pc0 * Bv[0] + pc1 * Bv[1] + pc2 * Bv[2] + pc3 * Bv[3];
    t1 = swzadd<0x401F>(t1); t1 = bp32add(t1);
    t2 = swzadd<0x401F>(t2); t2 = bp32add(t2);
    float sq = fmaxf(1.f + 2.f * t2 + t1, 0.f);
    float s = (sq / (sq + 1.f)) / fmaxf(sqrtf(sq), 1e-12f);
    float e0 = __expf(s * (Bv[0] + g0));
    float e1 = __expf(s * (Bv[1] + g1));
    float e2 = __expf(s * (Bv[2] + g2));
    float e3 = __expf(s * (Bv[3] + g3));
    float se = e0 + e1 + e2 + e3;
    se = swzadd<0x401F>(se); se = bp32add(se);
    float inv = __fdividef(1.f, se);
    pc0 = e0 * inv; pc1 = e1 * inv; pc2 = e2 * inv; pc3 = e3 * inv;
  }
  float selv = (msel == 0) ? pc0 : (msel == 1) ? pc1 : (msel == 2) ? pc2 : pc3;
  float2 xv = *(const float2*)(xn + (size_t)n * HD + 2 * lane);
  float u0 = xv.x, u1 = xv.y;
#pragma unroll
  for (int mm = 0; mm < MNB; ++mm) {
    int srcl = ((((mm >> 2) << 4) | (mm & 3)) << 2);
    float pm = __int_as_float(
        __builtin_amdgcn_ds_bpermute(srcl, __float_as_int(selv)));
    unsigned zv = *(const unsigned*)(zsh[w] + mm * 256 +
                                     ((4 * lane) ^ ((mm & 7) << 4)));
    float z0 = __int_as_float((zv & 0xFFFFu) << 16);
    float z1 = __int_as_float((zv >> 16) << 16);
    u0 += z0 * pm;
    u1 += z1 * pm;
  }
  *(float2*)(out + (size_t)n * HD + 2 * lane) = make_float2(u0, u1);
  float nsq = wsum(u0 * u0 + u1 * u1);
  float ninv = 1.f / fmaxf(sqrtf(nsq), 1e-12f);
  float na = u0 * ninv, nb = u1 * ninv;
  *(float2*)(onf + (size_t)n * HD + 2 * lane) = make_float2(na, nb);
  onb[(size_t)n * 64 + lane] = (unsigned)f2bf(na) | ((unsigned)f2bf(nb) << 16);
}

// ---------------- routing v3 (hop2): verbatim ------------------------------
__global__ __launch_bounds__(256) void routing_kernel(
    const float* __restrict__ xn, const unsigned* __restrict__ xnb,
    const int* __restrict__ adj, float* __restrict__ out) {
  __shared__ char zsh[4][4096];
  int tid = threadIdx.x;
  int w = tid >> 6, lane = tid & 63;
  int n = blockIdx.x * 4 + w;
  if (n >= N_IT) return;
  int m = lane & 15, quad = lane >> 4;
  const unsigned short* xb16 = (const unsigned short*)xnb;

  int idx = adj[n * MNB + m] - 1;
  const unsigned short* zrow = xb16 + (size_t)idx * HD;
  const unsigned short* xrow = xb16 + (size_t)n * HD;
  short8 zf[4], xf[4];
#pragma unroll
  for (int kk = 0; kk < 4; ++kk) {
    zf[kk] = *(const short8*)(zrow + kk * 32 + quad * 8);
    xf[kk] = *(const short8*)(xrow + kk * 32 + quad * 8);
  }
  f32x4 Gf = {0.f, 0.f, 0.f, 0.f}, Bv = {0.f, 0.f, 0.f, 0.f};
#pragma unroll
  for (int kk = 0; kk < 4; ++kk) {
    Gf = __builtin_amdgcn_mfma_f32_16x16x32_bf16(zf[kk], zf[kk], Gf, 0, 0, 0);
    Bv = __builtin_amdgcn_mfma_f32_16x16x32_bf16(zf[kk], xf[kk], Bv, 0, 0, 0);
  }
  char* zb = zsh[w] + m * 256;
#pragma unroll
  for (int kk = 0; kk < 4; ++kk)
    *(short8*)(zb + ((kk * 64 + quad * 16) ^ ((m & 7) << 4))) = zf[kk];

  float pc0 = 0.0625f, pc1 = 0.0625f, pc2 = 0.0625f, pc3 = 0.0625f;
  int msel = lane & 3;
  int cjaddr = (((lane >> 2) & 3) << 4 | (lane & 3)) << 2;

#pragma unroll
  for (int it = 0; it < 3; ++it) {
    float selv = (msel == 0) ? pc0 : (msel == 1) ? pc1 : (msel == 2) ? pc2 : pc3;
    float cj = __int_as_float(
        __builtin_amdgcn_ds_bpermute(cjaddr, __float_as_int(selv)));
    float g0 = Gf[0] * cj, g1 = Gf[1] * cj, g2 = Gf[2] * cj, g3 = Gf[3] * cj;
    g0 = dppadd<0xB1>(g0); g1 = dppadd<0xB1>(g1); g2 = dppadd<0xB1>(g2); g3 = dppadd<0xB1>(g3);
    g0 = dppadd<0x4E>(g0); g1 = dppadd<0x4E>(g1); g2 = dppadd<0x4E>(g2); g3 = dppadd<0x4E>(g3);
    g0 = swzadd<0x101F>(g0); g1 = swzadd<0x101F>(g1); g2 = swzadd<0x101F>(g2); g3 = swzadd<0x101F>(g3);
    g0 = swzadd<0x201F>(g0); g1 = swzadd<0x201F>(g1); g2 = swzadd<0x201F>(g2); g3 = swzadd<0x201F>(g3);
    float t1 = pc0 * g0 + pc1 * g1 + pc2 * g2 + pc3 * g3;
    float t2 = pc0 * Bv[0] + pc1 * Bv[1] + pc2 * Bv[2] + pc3 * Bv[3];
    t1 = swzadd<0x401F>(t1); t1 = bp32add(t1);
    t2 = swzadd<0x401F>(t2); t2 = bp32add(t2);
    float sq = fmaxf(1.f + 2.f * t2 + t1, 0.f);
    float s = (sq / (sq + 1.f)) / fmaxf(sqrtf(sq), 1e-12f);
    float e0 = __expf(s * (Bv[0] + g0));
    float e1 = __expf(s * (Bv[1] + g1));
    float e2 = __expf(s * (Bv[2] + g2));
    float e3 = __expf(s * (Bv[3] + g3));
    float se = e0 + e1 + e2 + e3;
    se = swzadd<0x401F>(se); se = bp32add(se);
    float inv = __fdividef(1.f, se);
    pc0 = e0 * inv; pc1 = e1 * inv; pc2 = e2 * inv; pc3 = e3 * inv;
  }
  float selv = (msel == 0) ? pc0 : (msel == 1) ? pc1 : (msel == 2) ? pc2 : pc3;
  float2 xv = *(const float2*)(xn + (size_t)n * HD + 2 * lane);
  float u0 = xv.x, u1 = xv.y;
#pragma unroll
  for (int mm = 0; mm < MNB; ++mm) {
    int srcl = ((((mm >> 2) << 4) | (mm & 3)) << 2);
    float pm = __int_as_float(
        __builtin_amdgcn_ds_bpermute(srcl, __float_as_int(selv)));
    unsigned zv = *(const unsigned*)(zsh[w] + mm * 256 +
                                     ((4 * lane) ^ ((mm & 7) << 4)));
    float z0 = __int_as_float((zv & 0xFFFFu) << 16);
    float z1 = __int_as_float((zv >> 16) << 16);
    u0 += z0 * pm;
    u1 += z1 * pm;
  }
  *(float2*)(out + (size_t)n * HD + 2 * lane) = make_float2(u0, u1);
}

// ---------------- iv table: lane owns d={2l,2l+1}; packed dword out --------
__global__ void iv_kernel(const float* __restrict__ item_emb,
                          const float* __restrict__ o1, const float* __restrict__ o2,
                          const float* __restrict__ g, const float* __restrict__ bb,
                          unsigned* __restrict__ tbf2) {
  int w = threadIdx.x >> 6, l = threadIdx.x & 63;
  int r = blockIdx.x * 4 + w;
  if (r >= NI) return;
  if (r == 0) {
    tbf2[l] = 0;
    return;
  }
  size_t pr = (size_t)(r - 1) * HD + 2 * l;
  float2 iev = *(const float2*)(item_emb + (size_t)r * HD + 2 * l);
  float2 o1v = *(const float2*)(o1 + pr);
  float2 o2v = *(const float2*)(o2 + pr);
  float a = iev.x + o1v.x + o2v.x;
  float b = iev.y + o1v.y + o2v.y;
  float mu = wsum(a + b) * (1.f / HD);
  float v  = wsum(a * a + b * b) * (1.f / HD) - mu * mu;
  float rs = rsqrtf(v + 1e-5f);
  float2 gv = *(const float2*)(g + 2 * l);
  float2 bv = *(const float2*)(bb + 2 * l);
  float va = (a - mu) * rs * gv.x + bv.x;
  float vb = (b - mu) * rs * gv.y + bv.y;
  tbf2[(size_t)r * 64 + l] = (unsigned)f2bf(va) | ((unsigned)f2bf(vb) << 16);
}

// ---------------- gi via MFMA, bf16 out, LDS-staged coalesced writes -------
__global__ __launch_bounds__(256) void gi2_kernel(
    const unsigned short* __restrict__ tbf, const unsigned short* __restrict__ cbf,
    const int* __restrict__ sess, const unsigned short* __restrict__ wbf,
    unsigned short* __restrict__ gib) {
  __shared__ int sidx[16];
  __shared__ unsigned short gtile[16 * G3];  // 12 KB
  int tid = threadIdx.x;
  int row0 = blockIdx.x * 16;
  if (tid < 16) sidx[tid] = sess[(row0 + tid) % 25600];
  __syncthreads();
  const unsigned short* src = (row0 < 25600) ? tbf : cbf;
  int w = tid >> 6, lane = tid & 63;
  int rloc = lane & 15, quad = lane >> 4;
  int arow = sidx[rloc];
  int ko = quad * 8;
  short8 A[4];
#pragma unroll
  for (int kk = 0; kk < 4; ++kk)
    A[kk] = *(const short8*)(src + (size_t)arow * HD + kk * 32 + ko);
#pragma unroll
  for (int s = 0; s < 6; ++s) {
    int jt = w * 6 + s;
    int j = jt * 16 + rloc;
    f32x4 acc = {0.f, 0.f, 0.f, 0.f};
#pragma unroll
    for (int kk = 0; kk < 4; ++kk) {
      short8 B = *(const short8*)(wbf + (size_t)j * HD + kk * 32 + ko);
      acc = __builtin_amdgcn_mfma_f32_16x16x32_bf16(A[kk], B, acc, 0, 0, 0);
    }
#pragma unroll
    for (int q = 0; q < 4; ++q)
      gtile[(quad * 4 + q) * G3 + jt * 16 + rloc] = f2bf(acc[q]);
  }
  __syncthreads();
  // 16 rows x 384 gates = 12288 B contiguous in gib: int4 copy (3/thread)
  const int4v* srcv = (const int4v*)gtile;
  int4v* dstv = (int4v*)(gib + (size_t)row0 * G3);
#pragma unroll
  for (int i = 0; i < 3; ++i)
    dstv[i * 256 + tid] = srcv[i * 256 + tid];
}

// ---------------- GRU recurrence via MFMA (gi bf16) ------------------------
__global__ __launch_bounds__(512) void gru_mfma_kernel(
    const unsigned short* __restrict__ gi_all, const float* __restrict__ Whh,
    const float* __restrict__ bih, const float* __restrict__ bhh,
    const int* __restrict__ lengths, float* __restrict__ ht_raw) {
  __shared__ unsigned short hlds[2][16 * HD];  // 8 KB
  int tid = threadIdx.x;
  int lane = tid & 63;
  int w = tid >> 6;
  int p = blockIdx.x >> 5;
  int r0 = (blockIdx.x & 31) * 16;
  int cN = lane & 15;
  int quad = lane >> 4;
  int d = w * 16 + cN;

  {
    int* hz = (int*)hlds;
    for (int i = tid; i < 2 * 16 * HD / 2; i += 512) hz[i] = 0;
  }

  short8 Br[4], Bz[4], Bn[4];
#pragma unroll
  for (int kk = 0; kk < 4; ++kk) {
    int kbase = quad * 8 + kk * 32;
    const float* wr_ = Whh + (size_t)d * HD + kbase;
    const float* wz_ = Whh + (size_t)(128 + d) * HD + kbase;
    const float* wn_ = Whh + (size_t)(256 + d) * HD + kbase;
    float4 r0v = *(const float4*)wr_, r1v = *(const float4*)(wr_ + 4);
    float4 z0v = *(const float4*)wz_, z1v = *(const float4*)(wz_ + 4);
    float4 n0v = *(const float4*)wn_, n1v = *(const float4*)(wn_ + 4);
    short8 br, bz, bn;
    br[0]=(short)f2bf(r0v.x); br[1]=(short)f2bf(r0v.y); br[2]=(short)f2bf(r0v.z); br[3]=(short)f2bf(r0v.w);
    br[4]=(short)f2bf(r1v.x); br[5]=(short)f2bf(r1v.y); br[6]=(short)f2bf(r1v.z); br[7]=(short)f2bf(r1v.w);
    bz[0]=(short)f2bf(z0v.x); bz[1]=(short)f2bf(z0v.y); bz[2]=(short)f2bf(z0v.z); bz[3]=(short)f2bf(z0v.w);
    bz[4]=(short)f2bf(z1v.x); bz[5]=(short)f2bf(z1v.y); bz[6]=(short)f2bf(z1v.z); bz[7]=(short)f2bf(z1v.w);
    bn[0]=(short)f2bf(n0v.x); bn[1]=(short)f2bf(n0v.y); bn[2]=(short)f2bf(n0v.z); bn[3]=(short)f2bf(n0v.w);
    bn[4]=(short)f2bf(n1v.x); bn[5]=(short)f2bf(n1v.y); bn[6]=(short)f2bf(n1v.z); bn[7]=(short)f2bf(n1v.w);
    Br[kk] = br; Bz[kk] = bz; Bn[kk] = bn;
  }
  float cr = bhh[d] + bih[d];
  float cz = bhh[128 + d] + bih[128 + d];
  float bhn = bhh[256 + d], bin = bih[256 + d];

  int lens4[4];
  float hold[4];
  const unsigned short* gptr[4];
#pragma unroll
  for (int gq = 0; gq < 4; ++gq) {
    int lr = quad * 4 + gq;
    lens4[gq] = lengths[r0 + lr] - 1;
    hold[gq] = 0.f;
    gptr[gq] = gi_all + ((size_t)p * 25600 + (size_t)(r0 + lr) * LSEQ) * G3 + d;
  }

  int aoff[4];
#pragma unroll
  for (int kk = 0; kk < 4; ++kk)
    aoff[kk] = cN * 256 + (((quad * 8 + kk * 32) * 2) ^ ((cN & 7) << 4));
  int woff[4];
#pragma unroll
  for (int gq = 0; gq < 4; ++gq) {
    int lr = quad * 4 + gq;
    woff[gq] = lr * 256 + ((2 * d) ^ ((lr & 7) << 4));
  }

  float giaR[4], giaZ[4], giaN[4];
#pragma unroll
  for (int gq = 0; gq < 4; ++gq) {
    giaR[gq] = bf2f(gptr[gq][0]);
    giaZ[gq] = bf2f(gptr[gq][HD]);
    giaN[gq] = bf2f(gptr[gq][2 * HD]);
  }
  __syncthreads();

  for (int t = 0; t < LSEQ; ++t) {
    float gbR[4], gbZ[4], gbN[4];
#pragma unroll
    for (int gq = 0; gq < 4; ++gq) {
      const unsigned short* gp = gptr[gq] + (size_t)(t + 1) * G3;
      gbR[gq] = bf2f(gp[0]); gbZ[gq] = bf2f(gp[HD]); gbN[gq] = bf2f(gp[2 * HD]);
    }
    const char* hb = (const char*)hlds[t & 1];
    f32x4 accR = {0.f, 0.f, 0.f, 0.f};
    f32x4 accZ = {0.f, 0.f, 0.f, 0.f};
    f32x4 accN = {0.f, 0.f, 0.f, 0.f};
#pragma unroll
    for (int kk = 0; kk < 4; ++kk) {
      short8 A = *(const short8*)(hb + aoff[kk]);
      accR = __builtin_amdgcn_mfma_f32_16x16x32_bf16(A, Br[kk], accR, 0, 0, 0);
      accZ = __builtin_amdgcn_mfma_f32_16x16x32_bf16(A, Bz[kk], accZ, 0, 0, 0);
      accN = __builtin_amdgcn_mfma_f32_16x16x32_bf16(A, Bn[kk], accN, 0, 0, 0);
    }
    char* hw = (char*)hlds[(t + 1) & 1];
#pragma unroll
    for (int gq = 0; gq < 4; ++gq) {
      float rg = fast_sigm(giaR[gq] + accR[gq] + cr);
      float zg = fast_sigm(giaZ[gq] + accZ[gq] + cz);
      float ng = fast_tanh(giaN[gq] + bin + rg * (accN[gq] + bhn));
      float hnew = (1.f - zg) * ng + zg * hold[gq];
      hold[gq] = hnew;
      *(unsigned short*)(hw + woff[gq]) = f2bf(hnew);
      if (t == lens4[gq])
        ht_raw[((size_t)p * BSZ + r0 + quad * 4 + gq) * HD + d] = hnew;
    }
    __syncthreads();
#pragma unroll
    for (int gq = 0; gq < 4; ++gq) {
      giaR[gq] = gbR[gq]; giaZ[gq] = gbZ[gq]; giaN[gq] = gbN[gq];
    }
  }
}

// ---------------- layernorm ht + bf16 copy ---------------------------------
__global__ void ln_ht_kernel(const float* __restrict__ ht,
                             const float* __restrict__ g2, const float* __restrict__ b2,
                             const float* __restrict__ g4, const float* __restrict__ b4,
                             unsigned short* __restrict__ hbf) {
  int w = threadIdx.x >> 6, l = threadIdx.x & 63;
  int r = blockIdx.x * 4 + w;
  if (r >= 2 * BSZ) return;
  const float* g = (r < BSZ) ? g2 : g4;
  const float* bb = (r < BSZ) ? b2 : b4;
  float a = ht[(size_t)r * HD + l];
  float b = ht[(size_t)r * HD + l + 64];
  float mu = wsum(a + b) * (1.f / HD);
  float v  = wsum(a * a + b * b) * (1.f / HD) - mu * mu;
  float rs = rsqrtf(v + 1e-5f);
  float va = (a - mu) * rs * g[l] + bb[l];
  float vb = (b - mu) * rs * g[l + 64] + bb[l + 64];
  hbf[(size_t)r * HD + l]      = f2bf(va);
  hbf[(size_t)r * HD + l + 64] = f2bf(vb);
}

// ---------------- scores: 32x32x16 MFMA + LDS-staged contiguous stores -----
#define JW 256
__global__ __launch_bounds__(512) void scores2_kernel(
    const unsigned short* __restrict__ hbf,
    const unsigned short* __restrict__ tbf,
    const unsigned short* __restrict__ cbf,
    const float* __restrict__ a1p, const float* __restrict__ a2p,
    float* __restrict__ out) {
  __shared__ float s1l[32 * JW];
  __shared__ float s2l[32 * JW];
  int tid = threadIdx.x;
  int w = tid >> 6, lane = tid & 63;
  int strip = blockIdx.x >> 4;
  int r0b = (blockIdx.x & 15) * 32;
  int j0 = strip * JW;
  int jc = j0 + w * 32 + (lane & 31);
  int jl = (jc < N_IT) ? jc : (N_IT - 1);
  int koA = (lane >> 5) * 8;

  f32x16 acc1 = {0.f}, acc2 = {0.f};
  const unsigned short* h1p = hbf + (size_t)(r0b + (lane & 31)) * HD + koA;
  const unsigned short* h2p = h1p + (size_t)BSZ * HD;
  const unsigned short* b1p = tbf + (size_t)(jl + 1) * HD + koA;
  const unsigned short* b2p = cbf + (size_t)(jl + 1) * HD + koA;
#pragma unroll
  for (int kk = 0; kk < 8; ++kk) {
    short8 A1 = *(const short8*)(h1p + kk * 16);
    short8 A2 = *(const short8*)(h2p + kk * 16);
    short8 B1 = *(const short8*)(b1p + kk * 16);
    short8 B2 = *(const short8*)(b2p + kk * 16);
    acc1 = __builtin_amdgcn_mfma_f32_32x32x16_bf16(A1, B1, acc1, 0, 0, 0);
    acc2 = __builtin_amdgcn_mfma_f32_32x32x16_bf16(A2, B2, acc2, 0, 0, 0);
  }
  int colb = w * 32 + (lane & 31);
#pragma unroll
  for (int q = 0; q < 16; ++q) {
    int row = (q & 3) + 8 * (q >> 2) + 4 * (lane >> 5);
    s1l[row * JW + colb] = acc1[q];
    s2l[row * JW + colb] = acc2[q];
  }
  __syncthreads();

  float sa1 = sigmf(a1p[0]);
  float sa2 = sigmf(a2p[0]);
  const size_t S = (size_t)BSZ * N_IT;
  bool full = (j0 + JW <= N_IT);
  if (full) {
#pragma unroll
    for (int pss = 0; pss < 16; ++pss) {
      int idx = pss * 512 + tid;
      int row = idx >> 8;
      int jlc = idx & 255;
      float s1 = s1l[idx];
      float s2 = s2l[idx];
      size_t o = (size_t)(r0b + row) * N_IT + j0 + jlc;
      out[o]         = sa1 * s1 + sa2 * s2;
      out[S + o]     = s1;
      out[2 * S + o] = s2;
    }
  } else {
#pragma unroll
    for (int pss = 0; pss < 16; ++pss) {
      int idx = pss * 512 + tid;
      int row = idx >> 8;
      int jlc = idx & 255;
      int jg = j0 + jlc;
      if (jg < N_IT) {
        float s1 = s1l[idx];
        float s2 = s2l[idx];
        size_t o = (size_t)(r0b + row) * N_IT + jg;
        out[o]         = sa1 * s1 + sa2 * s2;
        out[S + o]     = s1;
        out[2 * S + o] = s2;
      }
    }
  }
}

extern "C" void kernel_launch(void* const* d_in, const int* in_sizes, int n_in,
                              void* d_out, int out_size, void* d_ws, size_t ws_size,
                              hipStream_t stream) {
  const float* item_emb = (const float*)d_in[0];
  const float* prob_emb = (const float*)d_in[1];
  const float* W_cls    = (const float*)d_in[2];
  const float* a1       = (const float*)d_in[3];
  const float* a2       = (const float*)d_in[4];
  const float* Wih      = (const float*)d_in[5];
  const float* Whh      = (const float*)d_in[6];
  const float* bih      = (const float*)d_in[7];
  const float* bhh      = (const float*)d_in[8];
  const float* ln1_g = (const float*)d_in[9];
  const float* ln1_b = (const float*)d_in[10];
  const float* ln2_g = (const float*)d_in[11];
  const float* ln2_b = (const float*)d_in[12];
  const float* ln3_g = (const float*)d_in[13];
  const float* ln3_b = (const float*)d_in[14];
  const float* ln4_g = (const float*)d_in[15];
  const float* ln4_b = (const float*)d_in[16];
  const int* inp_sess = (const int*)d_in[19];
  const int* lengths  = (const int*)d_in[20];
  const int* adj      = (const int*)d_in[21];
  float* out = (float*)d_out;

  // Layout identical to R15 (lifetime-audited):
  //  xn | o1 | o2 | slot{x1f, x1b, cbf} | gi{xnb->gib, wbf@+10M} | htb
  float* ws = (float*)d_ws;
  const size_t SZ_ROW = (size_t)N_IT * HD;
  float* xn   = ws;
  float* o1   = xn + SZ_ROW;
  float* o2   = o1 + SZ_ROW;
  float* slot = o2 + SZ_ROW;                          // 12.8M floats
  float* x1f  = slot;                                 // 6.4M f32
  unsigned* x1b = (unsigned*)(slot + 6400000);        // 3.2M u32
  unsigned short* cbf = (unsigned short*)(slot + 9600000);  // 6.4M bf16
  float* gi  = slot + 2 * (size_t)NI * HD;
  float* htb = gi + (size_t)2 * 25600 * G3;

  unsigned* xnb = (unsigned*)gi;                      // dead before gib written
  unsigned short* gib = (unsigned short*)gi;          // bf16 gi
  unsigned short* wbf = (unsigned short*)(gi + 10000000);
  unsigned short* tbf = (unsigned short*)xn;          // written by iv
  unsigned short* hbf = (unsigned short*)o1;          // written by ln_ht

  int nb4 = (N_IT + 3) / 4;
  int nb4i = (NI + 3) / 4;

  prelude_kernel<<<25192, 256, 0, stream>>>(item_emb, xn, xnb,
                                            prob_emb, W_cls, ln3_g, ln3_b, cbf,
                                            Wih, wbf);
  routing1_kernel<<<nb4, 256, 0, stream>>>(xn, xnb, adj + MNB, o1, x1f, x1b);
  routing_kernel<<<nb4, 256, 0, stream>>>(x1f, x1b, adj + MNB, o2);
  iv_kernel<<<nb4i, 256, 0, stream>>>(item_emb, o1, o2, ln1_g, ln1_b,
                                      (unsigned*)tbf);
  gi2_kernel<<<3200, 256, 0, stream>>>(tbf, cbf, inp_sess, wbf, gib);
  gru_mfma_kernel<<<64, 512, 0, stream>>>(gib, Whh, bih, bhh, lengths, htb);
  ln_ht_kernel<<<256, 256, 0, stream>>>(htb, ln2_g, ln2_b, ln4_g, ln4_b, hbf);
  scores2_kernel<<<196 * 16, 512, 0, stream>>>(hbf, tbf, cbf, a1, a2, out);
}

// Round 17
// 394.309 us; speedup vs baseline: 1.0818x; 1.0308x over previous
//
#include <hip/hip_runtime.h>
#include <hip/hip_bf16.h>

#define N_IT 49999
#define NI   50000
#define HD   128
#define MNB  16
#define BSZ  512
#define LSEQ 50
#define G3   384

typedef __attribute__((ext_vector_type(8))) short short8;
typedef __attribute__((ext_vector_type(4))) float f32x4;
typedef __attribute__((ext_vector_type(16))) float f32x16;
typedef __attribute__((ext_vector_type(4))) int int4v;

__device__ __forceinline__ float sigmf(float x) {
  return 1.f / (1.f + __expf(-x));
}
__device__ __forceinline__ float fast_sigm(float x) {
  return __fdividef(1.f, 1.f + __expf(-x));
}
__device__ __forceinline__ float fast_tanh(float x) {
  float e = __expf(-2.f * x);
  return (1.f - e) * __fdividef(1.f, 1.f + e);
}

__device__ __forceinline__ unsigned short f2bf(float f) {
  unsigned u = __float_as_uint(f);
  u += 0x7FFF + ((u >> 16) & 1);
  return (unsigned short)(u >> 16);
}
__device__ __forceinline__ float bf2f(unsigned short v) {
  return __int_as_float(((unsigned)v) << 16);
}

// ---- DPP / swizzle butterfly helpers --------------------------------------
template <int CTRL>
__device__ __forceinline__ float dppadd(float v) {
  int s = __builtin_amdgcn_update_dpp(__float_as_int(v), __float_as_int(v),
                                      CTRL, 0xF, 0xF, false);
  return v + __int_as_float(s);
}
template <int MASK>
__device__ __forceinline__ float swzadd(float v) {
  return v + __int_as_float(__builtin_amdgcn_ds_swizzle(__float_as_int(v), MASK));
}
__device__ __forceinline__ float bp32add(float v) {
  int lane = threadIdx.x & 63;
  return v + __int_as_float(__builtin_amdgcn_ds_bpermute(((lane ^ 32) << 2),
                                                         __float_as_int(v)));
}

__device__ __forceinline__ float wsum(float v) {
  v = dppadd<0xB1>(v);    // i^1
  v = dppadd<0x4E>(v);    // i^2
  v = dppadd<0x141>(v);   // i^7 (row_half_mirror)
  v = dppadd<0x140>(v);   // i^15 (row_mirror)
  v = swzadd<0x401F>(v);  // i^16
  v = bp32add(v);         // i^32
  return v;
}

// ---------------- prelude: norm (item_emb) | cls table | Wih->bf16 ---------
__global__ void prelude_kernel(const float* __restrict__ item_emb,
                               float* __restrict__ xnf, unsigned* __restrict__ xnb,
                               const float* __restrict__ prob,
                               const float* __restrict__ Wc,
                               const float* __restrict__ g3v,
                               const float* __restrict__ b3v,
                               unsigned short* __restrict__ cbf,
                               const float* __restrict__ Wih,
                               unsigned short* __restrict__ wbf) {
  int b = blockIdx.x;
  if (b < 12500) {
    int w = threadIdx.x >> 6, l = threadIdx.x & 63;
    int r = b * 4 + w;
    if (r >= N_IT) return;
    const float* x = item_emb + HD;
    float2 xv = *(const float2*)(x + (size_t)r * HD + 2 * l);
    float sq = wsum(xv.x * xv.x + xv.y * xv.y);
    float inv = 1.f / fmaxf(sqrtf(sq), 1e-12f);
    float a = xv.x * inv, bb = xv.y * inv;
    *(float2*)(xnf + (size_t)r * HD + 2 * l) = make_float2(a, bb);
    xnb[(size_t)r * 64 + l] = (unsigned)f2bf(a) | ((unsigned)f2bf(bb) << 16);
  } else if (b < 25000) {
    int w = threadIdx.x >> 6, l = threadIdx.x & 63;
    int r = (b - 12500) * 4 + w;
    if (r >= NI) return;
    float p[10];
#pragma unroll
    for (int k = 0; k < 10; ++k) p[k] = prob[(size_t)r * 10 + k];
    float a = 0.f, bb = 0.f;
#pragma unroll
    for (int k = 0; k < 10; ++k) {
      a += p[k] * Wc[l * 10 + k];
      bb += p[k] * Wc[(l + 64) * 10 + k];
    }
    float mu = wsum(a + bb) * (1.f / HD);
    float v  = wsum(a * a + bb * bb) * (1.f / HD) - mu * mu;
    float rs = rsqrtf(v + 1e-5f);
    float va = (a - mu) * rs * g3v[l] + b3v[l];
    float vb = (bb - mu) * rs * g3v[l + 64] + b3v[l + 64];
    cbf[(size_t)r * HD + l]      = f2bf(va);
    cbf[(size_t)r * HD + l + 64] = f2bf(vb);
  } else {
    int i = (b - 25000) * 256 + threadIdx.x;
    if (i < 3 * HD * HD) wbf[i] = f2bf(Wih[i]);
  }
}

// ---------------- routing hop1 + fused normalize epilogue ------------------
__global__ __launch_bounds__(256) void routing1_kernel(
    const float* __restrict__ xn, const unsigned* __restrict__ xnb,
    const int* __restrict__ adj, float* __restrict__ out,
    float* __restrict__ onf, unsigned* __restrict__ onb) {
  __shared__ char zsh[4][4096];
  int tid = threadIdx.x;
  int w = tid >> 6, lane = tid & 63;
  int n = blockIdx.x * 4 + w;
  if (n >= N_IT) return;
  int m = lane & 15, quad = lane >> 4;
  const unsigned short* xb16 = (const unsigned short*)xnb;

  int idx = adj[n * MNB + m] - 1;
  const unsigned short* zrow = xb16 + (size_t)idx * HD;
  const unsigned short* xrow = xb16 + (size_t)n * HD;
  short8 zf[4], xf[4];
#pragma unroll
  for (int kk = 0; kk < 4; ++kk) {
    zf[kk] = *(const short8*)(zrow + kk * 32 + quad * 8);
    xf[kk] = *(const short8*)(xrow + kk * 32 + quad * 8);
  }
  f32x4 Gf = {0.f, 0.f, 0.f, 0.f}, Bv = {0.f, 0.f, 0.f, 0.f};
#pragma unroll
  for (int kk = 0; kk < 4; ++kk) {
    Gf = __builtin_amdgcn_mfma_f32_16x16x32_bf16(zf[kk], zf[kk], Gf, 0, 0, 0);
    Bv = __builtin_amdgcn_mfma_f32_16x16x32_bf16(zf[kk], xf[kk], Bv, 0, 0, 0);
  }
  char* zb = zsh[w] + m * 256;
#pragma unroll
  for (int kk = 0; kk < 4; ++kk)
    *(short8*)(zb + ((kk * 64 + quad * 16) ^ ((m & 7) << 4))) = zf[kk];

  float pc0 = 0.0625f, pc1 = 0.0625f, pc2 = 0.0625f, pc3 = 0.0625f;
  int msel = lane & 3;
  int cjaddr = (((lane >> 2) & 3) << 4 | (lane & 3)) << 2;

#pragma unroll
  for (int it = 0; it < 3; ++it) {
    float selv = (msel == 0) ? pc0 : (msel == 1) ? pc1 : (msel == 2) ? pc2 : pc3;
    float cj = __int_as_float(
        __builtin_amdgcn_ds_bpermute(cjaddr, __float_as_int(selv)));
    float g0 = Gf[0] * cj, g1 = Gf[1] * cj, g2 = Gf[2] * cj, g3 = Gf[3] * cj;
    g0 = dppadd<0xB1>(g0); g1 = dppadd<0xB1>(g1); g2 = dppadd<0xB1>(g2); g3 = dppadd<0xB1>(g3);
    g0 = dppadd<0x4E>(g0); g1 = dppadd<0x4E>(g1); g2 = dppadd<0x4E>(g2); g3 = dppadd<0x4E>(g3);
    g0 = swzadd<0x101F>(g0); g1 = swzadd<0x101F>(g1); g2 = swzadd<0x101F>(g2); g3 = swzadd<0x101F>(g3);
    g0 = swzadd<0x201F>(g0); g1 = swzadd<0x201F>(g1); g2 = swzadd<0x201F>(g2); g3 = swzadd<0x201F>(g3);
    float t1 = pc0 * g0 + pc1 * g1 + pc2 * g2 + pc3 * g3;
    float t2 = pc0 * Bv[0] + pc1 * Bv[1] + pc2 * Bv[2] + pc3 * Bv[3];
    t1 = swzadd<0x401F>(t1); t1 = bp32add(t1);
    t2 = swzadd<0x401F>(t2); t2 = bp32add(t2);
    float sq = fmaxf(1.f + 2.f * t2 + t1, 0.f);
    float s = (sq / (sq + 1.f)) / fmaxf(sqrtf(sq), 1e-12f);
    float e0 = __expf(s * (Bv[0] + g0));
    float e1 = __expf(s * (Bv[1] + g1));
    float e2 = __expf(s * (Bv[2] + g2));
    float e3 = __expf(s * (Bv[3] + g3));
    float se = e0 + e1 + e2 + e3;
    se = swzadd<0x401F>(se); se = bp32add(se);
    float inv = __fdividef(1.f, se);
    pc0 = e0 * inv; pc1 = e1 * inv; pc2 = e2 * inv; pc3 = e3 * inv;
  }
  float selv = (msel == 0) ? pc0 : (msel == 1) ? pc1 : (msel == 2) ? pc2 : pc3;
  float2 xv = *(const float2*)(xn + (size_t)n * HD + 2 * lane);
  float u0 = xv.x, u1 = xv.y;
#pragma unroll
  for (int mm = 0; mm < MNB; ++mm) {
    int srcl = ((((mm >> 2) << 4) | (mm & 3)) << 2);
    float pm = __int_as_float(
        __builtin_amdgcn_ds_bpermute(srcl, __float_as_int(selv)));
    unsigned zv = *(const unsigned*)(zsh[w] + mm * 256 +
                                     ((4 * lane) ^ ((mm & 7) << 4)));
    float z0 = __int_as_float((zv & 0xFFFFu) << 16);
    float z1 = __int_as_float((zv >> 16) << 16);
    u0 += z0 * pm;
    u1 += z1 * pm;
  }
  *(float2*)(out + (size_t)n * HD + 2 * lane) = make_float2(u0, u1);
  float nsq = wsum(u0 * u0 + u1 * u1);
  float ninv = 1.f / fmaxf(sqrtf(nsq), 1e-12f);
  float na = u0 * ninv, nb = u1 * ninv;
  *(float2*)(onf + (size_t)n * HD + 2 * lane) = make_float2(na, nb);
  onb[(size_t)n * 64 + lane] = (unsigned)f2bf(na) | ((unsigned)f2bf(nb) << 16);
}

// ---------------- routing v3 (hop2): verbatim ------------------------------
__global__ __launch_bounds__(256) void routing_kernel(
    const float* __restrict__ xn, const unsigned* __restrict__ xnb,
    const int* __restrict__ adj, float* __restrict__ out) {
  __shared__ char zsh[4][4096];
  int tid = threadIdx.x;
  int w = tid >> 6, lane = tid & 63;
  int n = blockIdx.x * 4 + w;
  if (n >= N_IT) return;
  int m = lane & 15, quad = lane >> 4;
  const unsigned short* xb16 = (const unsigned short*)xnb;

  int idx = adj[n * MNB + m] - 1;
  const unsigned short* zrow = xb16 + (size_t)idx * HD;
  const unsigned short* xrow = xb16 + (size_t)n * HD;
  short8 zf[4], xf[4];
#pragma unroll
  for (int kk = 0; kk < 4; ++kk) {
    zf[kk] = *(const short8*)(zrow + kk * 32 + quad * 8);
    xf[kk] = *(const short8*)(xrow + kk * 32 + quad * 8);
  }
  f32x4 Gf = {0.f, 0.f, 0.f, 0.f}, Bv = {0.f, 0.f, 0.f, 0.f};
#pragma unroll
  for (int kk = 0; kk < 4; ++kk) {
    Gf = __builtin_amdgcn_mfma_f32_16x16x32_bf16(zf[kk], zf[kk], Gf, 0, 0, 0);
    Bv = __builtin_amdgcn_mfma_f32_16x16x32_bf16(zf[kk], xf[kk], Bv, 0, 0, 0);
  }
  char* zb = zsh[w] + m * 256;
#pragma unroll
  for (int kk = 0; kk < 4; ++kk)
    *(short8*)(zb + ((kk * 64 + quad * 16) ^ ((m & 7) << 4))) = zf[kk];

  float pc0 = 0.0625f, pc1 = 0.0625f, pc2 = 0.0625f, pc3 = 0.0625f;
  int msel = lane & 3;
  int cjaddr = (((lane >> 2) & 3) << 4 | (lane & 3)) << 2;

#pragma unroll
  for (int it = 0; it < 3; ++it) {
    float selv = (msel == 0) ? pc0 : (msel == 1) ? pc1 : (msel == 2) ? pc2 : pc3;
    float cj = __int_as_float(
        __builtin_amdgcn_ds_bpermute(cjaddr, __float_as_int(selv)));
    float g0 = Gf[0] * cj, g1 = Gf[1] * cj, g2 = Gf[2] * cj, g3 = Gf[3] * cj;
    g0 = dppadd<0xB1>(g0); g1 = dppadd<0xB1>(g1); g2 = dppadd<0xB1>(g2); g3 = dppadd<0xB1>(g3);
    g0 = dppadd<0x4E>(g0); g1 = dppadd<0x4E>(g1); g2 = dppadd<0x4E>(g2); g3 = dppadd<0x4E>(g3);
    g0 = swzadd<0x101F>(g0); g1 = swzadd<0x101F>(g1); g2 = swzadd<0x101F>(g2); g3 = swzadd<0x101F>(g3);
    g0 = swzadd<0x201F>(g0); g1 = swzadd<0x201F>(g1); g2 = swzadd<0x201F>(g2); g3 = swzadd<0x201F>(g3);
    float t1 = pc0 * g0 + pc1 * g1 + pc2 * g2 + pc3 * g3;
    float t2 = pc0 * Bv[0] + pc1 * Bv[1] + pc2 * Bv[2] + pc3 * Bv[3];
    t1 = swzadd<0x401F>(t1); t1 = bp32add(t1);
    t2 = swzadd<0x401F>(t2); t2 = bp32add(t2);
    float sq = fmaxf(1.f + 2.f * t2 + t1, 0.f);
    float s = (sq / (sq + 1.f)) / fmaxf(sqrtf(sq), 1e-12f);
    float e0 = __expf(s * (Bv[0] + g0));
    float e1 = __expf(s * (Bv[1] + g1));
    float e2 = __expf(s * (Bv[2] + g2));
    float e3 = __expf(s * (Bv[3] + g3));
    float se = e0 + e1 + e2 + e3;
    se = swzadd<0x401F>(se); se = bp32add(se);
    float inv = __fdividef(1.f, se);
    pc0 = e0 * inv; pc1 = e1 * inv; pc2 = e2 * inv; pc3 = e3 * inv;
  }
  float selv = (msel == 0) ? pc0 : (msel == 1) ? pc1 : (msel == 2) ? pc2 : pc3;
  float2 xv = *(const float2*)(xn + (size_t)n * HD + 2 * lane);
  float u0 = xv.x, u1 = xv.y;
#pragma unroll
  for (int mm = 0; mm < MNB; ++mm) {
    int srcl = ((((mm >> 2) << 4) | (mm & 3)) << 2);
    float pm = __int_as_float(
        __builtin_amdgcn_ds_bpermute(srcl, __float_as_int(selv)));
    unsigned zv = *(const unsigned*)(zsh[w] + mm * 256 +
                                     ((4 * lane) ^ ((mm & 7) << 4)));
    float z0 = __int_as_float((zv & 0xFFFFu) << 16);
    float z1 = __int_as_float((zv >> 16) << 16);
    u0 += z0 * pm;
    u1 += z1 * pm;
  }
  *(float2*)(out + (size_t)n * HD + 2 * lane) = make_float2(u0, u1);
}

// ---------------- iv table: lane owns d={2l,2l+1}; packed dword out --------
__global__ void iv_kernel(const float* __restrict__ item_emb,
                          const float* __restrict__ o1, const float* __restrict__ o2,
                          const float* __restrict__ g, const float* __restrict__ bb,
                          unsigned* __restrict__ tbf2) {
  int w = threadIdx.x >> 6, l = threadIdx.x & 63;
  int r = blockIdx.x * 4 + w;
  if (r >= NI) return;
  if (r == 0) {
    tbf2[l] = 0;
    return;
  }
  size_t pr = (size_t)(r - 1) * HD + 2 * l;
  float2 iev = *(const float2*)(item_emb + (size_t)r * HD + 2 * l);
  float2 o1v = *(const float2*)(o1 + pr);
  float2 o2v = *(const float2*)(o2 + pr);
  float a = iev.x + o1v.x + o2v.x;
  float b = iev.y + o1v.y + o2v.y;
  float mu = wsum(a + b) * (1.f / HD);
  float v  = wsum(a * a + b * b) * (1.f / HD) - mu * mu;
  float rs = rsqrtf(v + 1e-5f);
  float2 gv = *(const float2*)(g + 2 * l);
  float2 bv = *(const float2*)(bb + 2 * l);
  float va = (a - mu) * rs * gv.x + bv.x;
  float vb = (b - mu) * rs * gv.y + bv.y;
  tbf2[(size_t)r * 64 + l] = (unsigned)f2bf(va) | ((unsigned)f2bf(vb) << 16);
}

// ---------------- gi via MFMA, bf16 out, LDS-staged coalesced writes -------
__global__ __launch_bounds__(256) void gi2_kernel(
    const unsigned short* __restrict__ tbf, const unsigned short* __restrict__ cbf,
    const int* __restrict__ sess, const unsigned short* __restrict__ wbf,
    unsigned short* __restrict__ gib) {
  __shared__ int sidx[16];
  __shared__ unsigned short gtile[16 * G3];  // 12 KB
  int tid = threadIdx.x;
  int row0 = blockIdx.x * 16;
  if (tid < 16) sidx[tid] = sess[(row0 + tid) % 25600];
  __syncthreads();
  const unsigned short* src = (row0 < 25600) ? tbf : cbf;
  int w = tid >> 6, lane = tid & 63;
  int rloc = lane & 15, quad = lane >> 4;
  int arow = sidx[rloc];
  int ko = quad * 8;
  short8 A[4];
#pragma unroll
  for (int kk = 0; kk < 4; ++kk)
    A[kk] = *(const short8*)(src + (size_t)arow * HD + kk * 32 + ko);
#pragma unroll
  for (int s = 0; s < 6; ++s) {
    int jt = w * 6 + s;
    int j = jt * 16 + rloc;
    f32x4 acc = {0.f, 0.f, 0.f, 0.f};
#pragma unroll
    for (int kk = 0; kk < 4; ++kk) {
      short8 B = *(const short8*)(wbf + (size_t)j * HD + kk * 32 + ko);
      acc = __builtin_amdgcn_mfma_f32_16x16x32_bf16(A[kk], B, acc, 0, 0, 0);
    }
#pragma unroll
    for (int q = 0; q < 4; ++q)
      gtile[(quad * 4 + q) * G3 + jt * 16 + rloc] = f2bf(acc[q]);
  }
  __syncthreads();
  const int4v* srcv = (const int4v*)gtile;
  int4v* dstv = (int4v*)(gib + (size_t)row0 * G3);
#pragma unroll
  for (int i = 0; i < 3; ++i)
    dstv[i * 256 + tid] = srcv[i * 256 + tid];
}

// ---------------- GRU recurrence via MFMA (gi bf16) ------------------------
__global__ __launch_bounds__(512) void gru_mfma_kernel(
    const unsigned short* __restrict__ gi_all, const float* __restrict__ Whh,
    const float* __restrict__ bih, const float* __restrict__ bhh,
    const int* __restrict__ lengths, float* __restrict__ ht_raw) {
  __shared__ unsigned short hlds[2][16 * HD];  // 8 KB
  int tid = threadIdx.x;
  int lane = tid & 63;
  int w = tid >> 6;
  int p = blockIdx.x >> 5;
  int r0 = (blockIdx.x & 31) * 16;
  int cN = lane & 15;
  int quad = lane >> 4;
  int d = w * 16 + cN;

  {
    int* hz = (int*)hlds;
    for (int i = tid; i < 2 * 16 * HD / 2; i += 512) hz[i] = 0;
  }

  short8 Br[4], Bz[4], Bn[4];
#pragma unroll
  for (int kk = 0; kk < 4; ++kk) {
    int kbase = quad * 8 + kk * 32;
    const float* wr_ = Whh + (size_t)d * HD + kbase;
    const float* wz_ = Whh + (size_t)(128 + d) * HD + kbase;
    const float* wn_ = Whh + (size_t)(256 + d) * HD + kbase;
    float4 r0v = *(const float4*)wr_, r1v = *(const float4*)(wr_ + 4);
    float4 z0v = *(const float4*)wz_, z1v = *(const float4*)(wz_ + 4);
    float4 n0v = *(const float4*)wn_, n1v = *(const float4*)(wn_ + 4);
    short8 br, bz, bn;
    br[0]=(short)f2bf(r0v.x); br[1]=(short)f2bf(r0v.y); br[2]=(short)f2bf(r0v.z); br[3]=(short)f2bf(r0v.w);
    br[4]=(short)f2bf(r1v.x); br[5]=(short)f2bf(r1v.y); br[6]=(short)f2bf(r1v.z); br[7]=(short)f2bf(r1v.w);
    bz[0]=(short)f2bf(z0v.x); bz[1]=(short)f2bf(z0v.y); bz[2]=(short)f2bf(z0v.z); bz[3]=(short)f2bf(z0v.w);
    bz[4]=(short)f2bf(z1v.x); bz[5]=(short)f2bf(z1v.y); bz[6]=(short)f2bf(z1v.z); bz[7]=(short)f2bf(z1v.w);
    bn[0]=(short)f2bf(n0v.x); bn[1]=(short)f2bf(n0v.y); bn[2]=(short)f2bf(n0v.z); bn[3]=(short)f2bf(n0v.w);
    bn[4]=(short)f2bf(n1v.x); bn[5]=(short)f2bf(n1v.y); bn[6]=(short)f2bf(n1v.z); bn[7]=(short)f2bf(n1v.w);
    Br[kk] = br; Bz[kk] = bz; Bn[kk] = bn;
  }
  float cr = bhh[d] + bih[d];
  float cz = bhh[128 + d] + bih[128 + d];
  float bhn = bhh[256 + d], bin = bih[256 + d];

  int lens4[4];
  float hold[4];
  const unsigned short* gptr[4];
#pragma unroll
  for (int gq = 0; gq < 4; ++gq) {
    int lr = quad * 4 + gq;
    lens4[gq] = lengths[r0 + lr] - 1;
    hold[gq] = 0.f;
    gptr[gq] = gi_all + ((size_t)p * 25600 + (size_t)(r0 + lr) * LSEQ) * G3 + d;
  }

  int aoff[4];
#pragma unroll
  for (int kk = 0; kk < 4; ++kk)
    aoff[kk] = cN * 256 + (((quad * 8 + kk * 32) * 2) ^ ((cN & 7) << 4));
  int woff[4];
#pragma unroll
  for (int gq = 0; gq < 4; ++gq) {
    int lr = quad * 4 + gq;
    woff[gq] = lr * 256 + ((2 * d) ^ ((lr & 7) << 4));
  }

  float giaR[4], giaZ[4], giaN[4];
#pragma unroll
  for (int gq = 0; gq < 4; ++gq) {
    giaR[gq] = bf2f(gptr[gq][0]);
    giaZ[gq] = bf2f(gptr[gq][HD]);
    giaN[gq] = bf2f(gptr[gq][2 * HD]);
  }
  __syncthreads();

  for (int t = 0; t < LSEQ; ++t) {
    float gbR[4], gbZ[4], gbN[4];
#pragma unroll
    for (int gq = 0; gq < 4; ++gq) {
      const unsigned short* gp = gptr[gq] + (size_t)(t + 1) * G3;
      gbR[gq] = bf2f(gp[0]); gbZ[gq] = bf2f(gp[HD]); gbN[gq] = bf2f(gp[2 * HD]);
    }
    const char* hb = (const char*)hlds[t & 1];
    f32x4 accR = {0.f, 0.f, 0.f, 0.f};
    f32x4 accZ = {0.f, 0.f, 0.f, 0.f};
    f32x4 accN = {0.f, 0.f, 0.f, 0.f};
#pragma unroll
    for (int kk = 0; kk < 4; ++kk) {
      short8 A = *(const short8*)(hb + aoff[kk]);
      accR = __builtin_amdgcn_mfma_f32_16x16x32_bf16(A, Br[kk], accR, 0, 0, 0);
      accZ = __builtin_amdgcn_mfma_f32_16x16x32_bf16(A, Bz[kk], accZ, 0, 0, 0);
      accN = __builtin_amdgcn_mfma_f32_16x16x32_bf16(A, Bn[kk], accN, 0, 0, 0);
    }
    char* hw = (char*)hlds[(t + 1) & 1];
#pragma unroll
    for (int gq = 0; gq < 4; ++gq) {
      float rg = fast_sigm(giaR[gq] + accR[gq] + cr);
      float zg = fast_sigm(giaZ[gq] + accZ[gq] + cz);
      float ng = fast_tanh(giaN[gq] + bin + rg * (accN[gq] + bhn));
      float hnew = (1.f - zg) * ng + zg * hold[gq];
      hold[gq] = hnew;
      *(unsigned short*)(hw + woff[gq]) = f2bf(hnew);
      if (t == lens4[gq])
        ht_raw[((size_t)p * BSZ + r0 + quad * 4 + gq) * HD + d] = hnew;
    }
    __syncthreads();
#pragma unroll
    for (int gq = 0; gq < 4; ++gq) {
      giaR[gq] = gbR[gq]; giaZ[gq] = gbZ[gq]; giaN[gq] = gbN[gq];
    }
  }
}

// ---------------- layernorm ht + bf16 copy ---------------------------------
__global__ void ln_ht_kernel(const float* __restrict__ ht,
                             const float* __restrict__ g2, const float* __restrict__ b2,
                             const float* __restrict__ g4, const float* __restrict__ b4,
                             unsigned short* __restrict__ hbf) {
  int w = threadIdx.x >> 6, l = threadIdx.x & 63;
  int r = blockIdx.x * 4 + w;
  if (r >= 2 * BSZ) return;
  const float* g = (r < BSZ) ? g2 : g4;
  const float* bb = (r < BSZ) ? b2 : b4;
  float a = ht[(size_t)r * HD + l];
  float b = ht[(size_t)r * HD + l + 64];
  float mu = wsum(a + b) * (1.f / HD);
  float v  = wsum(a * a + b * b) * (1.f / HD) - mu * mu;
  float rs = rsqrtf(v + 1e-5f);
  float va = (a - mu) * rs * g[l] + bb[l];
  float vb = (b - mu) * rs * g[l + 64] + bb[l + 64];
  hbf[(size_t)r * HD + l]      = f2bf(va);
  hbf[(size_t)r * HD + l + 64] = f2bf(vb);
}

// ---------------- scores: B-reuse x4 row-groups per block ------------------
// grid 196*4: strip = bid>>2, row-quarter = bid&3 (128 rows, 4 passes of 32).
// B-fragments loaded ONCE into registers; LDS staging + contiguous stores per pass.
#define JW 256
__global__ __launch_bounds__(512) void scores3_kernel(
    const unsigned short* __restrict__ hbf,
    const unsigned short* __restrict__ tbf,
    const unsigned short* __restrict__ cbf,
    const float* __restrict__ a1p, const float* __restrict__ a2p,
    float* __restrict__ out) {
  __shared__ float s1l[32 * JW];
  __shared__ float s2l[32 * JW];
  int tid = threadIdx.x;
  int w = tid >> 6, lane = tid & 63;
  int strip = blockIdx.x >> 2;
  int rq = blockIdx.x & 3;
  int j0 = strip * JW;
  int jc = j0 + w * 32 + (lane & 31);
  int jl = (jc < N_IT) ? jc : (N_IT - 1);
  int koA = (lane >> 5) * 8;

  short8 B1[8], B2[8];
  const unsigned short* b1p = tbf + (size_t)(jl + 1) * HD + koA;
  const unsigned short* b2p = cbf + (size_t)(jl + 1) * HD + koA;
#pragma unroll
  for (int kk = 0; kk < 8; ++kk) {
    B1[kk] = *(const short8*)(b1p + kk * 16);
    B2[kk] = *(const short8*)(b2p + kk * 16);
  }
  float sa1 = sigmf(a1p[0]);
  float sa2 = sigmf(a2p[0]);
  const size_t S = (size_t)BSZ * N_IT;
  int colb = w * 32 + (lane & 31);
  bool full = (j0 + JW <= N_IT);

  for (int ps = 0; ps < 4; ++ps) {
    int r0b = rq * 128 + ps * 32;
    f32x16 acc1 = {0.f}, acc2 = {0.f};
    const unsigned short* h1p = hbf + (size_t)(r0b + (lane & 31)) * HD + koA;
    const unsigned short* h2p = h1p + (size_t)BSZ * HD;
#pragma unroll
    for (int kk = 0; kk < 8; ++kk) {
      short8 A1 = *(const short8*)(h1p + kk * 16);
      short8 A2 = *(const short8*)(h2p + kk * 16);
      acc1 = __builtin_amdgcn_mfma_f32_32x32x16_bf16(A1, B1[kk], acc1, 0, 0, 0);
      acc2 = __builtin_amdgcn_mfma_f32_32x32x16_bf16(A2, B2[kk], acc2, 0, 0, 0);
    }
#pragma unroll
    for (int q = 0; q < 16; ++q) {
      int row = (q & 3) + 8 * (q >> 2) + 4 * (lane >> 5);
      s1l[row * JW + colb] = acc1[q];
      s2l[row * JW + colb] = acc2[q];
    }
    __syncthreads();

    if (full) {
#pragma unroll
      for (int pss = 0; pss < 16; ++pss) {
        int idx = pss * 512 + tid;
        int row = idx >> 8;
        int jlc = idx & 255;
        float s1 = s1l[idx];
        float s2 = s2l[idx];
        size_t o = (size_t)(r0b + row) * N_IT + j0 + jlc;
        out[o]         = sa1 * s1 + sa2 * s2;
        out[S + o]     = s1;
        out[2 * S + o] = s2;
      }
    } else {
#pragma unroll
      for (int pss = 0; pss < 16; ++pss) {
        int idx = pss * 512 + tid;
        int row = idx >> 8;
        int jlc = idx & 255;
        int jg = j0 + jlc;
        if (jg < N_IT) {
          float s1 = s1l[idx];
          float s2 = s2l[idx];
          size_t o = (size_t)(r0b + row) * N_IT + jg;
          out[o]         = sa1 * s1 + sa2 * s2;
          out[S + o]     = s1;
          out[2 * S + o] = s2;
        }
      }
    }
    __syncthreads();
  }
}

extern "C" void kernel_launch(void* const* d_in, const int* in_sizes, int n_in,
                              void* d_out, int out_size, void* d_ws, size_t ws_size,
                              hipStream_t stream) {
  const float* item_emb = (const float*)d_in[0];
  const float* prob_emb = (const float*)d_in[1];
  const float* W_cls    = (const float*)d_in[2];
  const float* a1       = (const float*)d_in[3];
  const float* a2       = (const float*)d_in[4];
  const float* Wih      = (const float*)d_in[5];
  const float* Whh      = (const float*)d_in[6];
  const float* bih      = (const float*)d_in[7];
  const float* bhh      = (const float*)d_in[8];
  const float* ln1_g = (const float*)d_in[9];
  const float* ln1_b = (const float*)d_in[10];
  const float* ln2_g = (const float*)d_in[11];
  const float* ln2_b = (const float*)d_in[12];
  const float* ln3_g = (const float*)d_in[13];
  const float* ln3_b = (const float*)d_in[14];
  const float* ln4_g = (const float*)d_in[15];
  const float* ln4_b = (const float*)d_in[16];
  const int* inp_sess = (const int*)d_in[19];
  const int* lengths  = (const int*)d_in[20];
  const int* adj      = (const int*)d_in[21];
  float* out = (float*)d_out;

  // Layout identical to R15/R16 (lifetime-audited).
  float* ws = (float*)d_ws;
  const size_t SZ_ROW = (size_t)N_IT * HD;
  float* xn   = ws;
  float* o1   = xn + SZ_ROW;
  float* o2   = o1 + SZ_ROW;
  float* slot = o2 + SZ_ROW;
  float* x1f  = slot;
  unsigned* x1b = (unsigned*)(slot + 6400000);
  unsigned short* cbf = (unsigned short*)(slot + 9600000);
  float* gi  = slot + 2 * (size_t)NI * HD;
  float* htb = gi + (size_t)2 * 25600 * G3;

  unsigned* xnb = (unsigned*)gi;
  unsigned short* gib = (unsigned short*)gi;
  unsigned short* wbf = (unsigned short*)(gi + 10000000);
  unsigned short* tbf = (unsigned short*)xn;
  unsigned short* hbf = (unsigned short*)o1;

  int nb4 = (N_IT + 3) / 4;
  int nb4i = (NI + 3) / 4;

  prelude_kernel<<<25192, 256, 0, stream>>>(item_emb, xn, xnb,
                                            prob_emb, W_cls, ln3_g, ln3_b, cbf,
                                            Wih, wbf);
  routing1_kernel<<<nb4, 256, 0, stream>>>(xn, xnb, adj + MNB, o1, x1f, x1b);
  routing_kernel<<<nb4, 256, 0, stream>>>(x1f, x1b, adj + MNB, o2);
  iv_kernel<<<nb4i, 256, 0, stream>>>(item_emb, o1, o2, ln1_g, ln1_b,
                                      (unsigned*)tbf);
  gi2_kernel<<<3200, 256, 0, stream>>>(tbf, cbf, inp_sess, wbf, gib);
  gru_mfma_kernel<<<64, 512, 0, stream>>>(gib, Whh, bih, bhh, lengths, htb);
  ln_ht_kernel<<<256, 256, 0, stream>>>(htb, ln2_g, ln2_b, ln4_g, ln4_b, hbf);
  scores3_kernel<<<196 * 4, 512, 0, stream>>>(hbf, tbf, cbf, a1, a2, out);
}

// Round 18
// 389.854 us; speedup vs baseline: 1.0941x; 1.0114x over previous
//
#include <hip/hip_runtime.h>
#include <hip/hip_bf16.h>

#define N_IT 49999
#define NI   50000
#define HD   128
#define MNB  16
#define BSZ  512
#define LSEQ 50
#define G3   384

typedef __attribute__((ext_vector_type(8))) short short8;
typedef __attribute__((ext_vector_type(4))) float f32x4;
typedef __attribute__((ext_vector_type(16))) float f32x16;
typedef __attribute__((ext_vector_type(4))) int int4v;

__device__ __forceinline__ float sigmf(float x) {
  return 1.f / (1.f + __expf(-x));
}
__device__ __forceinline__ float fast_sigm(float x) {
  return __fdividef(1.f, 1.f + __expf(-x));
}
__device__ __forceinline__ float fast_tanh(float x) {
  float e = __expf(-2.f * x);
  return (1.f - e) * __fdividef(1.f, 1.f + e);
}

__device__ __forceinline__ unsigned short f2bf(float f) {
  unsigned u = __float_as_uint(f);
  u += 0x7FFF + ((u >> 16) & 1);
  return (unsigned short)(u >> 16);
}
__device__ __forceinline__ float bf2f(unsigned short v) {
  return __int_as_float(((unsigned)v) << 16);
}

// ---- DPP / swizzle butterfly helpers --------------------------------------
template <int CTRL>
__device__ __forceinline__ float dppadd(float v) {
  int s = __builtin_amdgcn_update_dpp(__float_as_int(v), __float_as_int(v),
                                      CTRL, 0xF, 0xF, false);
  return v + __int_as_float(s);
}
template <int MASK>
__device__ __forceinline__ float swzadd(float v) {
  return v + __int_as_float(__builtin_amdgcn_ds_swizzle(__float_as_int(v), MASK));
}
__device__ __forceinline__ float bp32add(float v) {
  int lane = threadIdx.x & 63;
  return v + __int_as_float(__builtin_amdgcn_ds_bpermute(((lane ^ 32) << 2),
                                                         __float_as_int(v)));
}

__device__ __forceinline__ float wsum(float v) {
  v = dppadd<0xB1>(v);    // i^1
  v = dppadd<0x4E>(v);    // i^2
  v = dppadd<0x141>(v);   // i^7 (row_half_mirror)
  v = dppadd<0x140>(v);   // i^15 (row_mirror)
  v = swzadd<0x401F>(v);  // i^16
  v = bp32add(v);         // i^32
  return v;
}

// ---------------- prelude: norm (item_emb) | cls table | Wih->bf16 ---------
__global__ void prelude_kernel(const float* __restrict__ item_emb,
                               float* __restrict__ xnf, unsigned* __restrict__ xnb,
                               const float* __restrict__ prob,
                               const float* __restrict__ Wc,
                               const float* __restrict__ g3v,
                               const float* __restrict__ b3v,
                               unsigned short* __restrict__ cbf,
                               const float* __restrict__ Wih,
                               unsigned short* __restrict__ wbf) {
  int b = blockIdx.x;
  if (b < 12500) {
    int w = threadIdx.x >> 6, l = threadIdx.x & 63;
    int r = b * 4 + w;
    if (r >= N_IT) return;
    const float* x = item_emb + HD;
    float2 xv = *(const float2*)(x + (size_t)r * HD + 2 * l);
    float sq = wsum(xv.x * xv.x + xv.y * xv.y);
    float inv = 1.f / fmaxf(sqrtf(sq), 1e-12f);
    float a = xv.x * inv, bb = xv.y * inv;
    *(float2*)(xnf + (size_t)r * HD + 2 * l) = make_float2(a, bb);
    xnb[(size_t)r * 64 + l] = (unsigned)f2bf(a) | ((unsigned)f2bf(bb) << 16);
  } else if (b < 25000) {
    int w = threadIdx.x >> 6, l = threadIdx.x & 63;
    int r = (b - 12500) * 4 + w;
    if (r >= NI) return;
    float p[10];
#pragma unroll
    for (int k = 0; k < 10; ++k) p[k] = prob[(size_t)r * 10 + k];
    float a = 0.f, bb = 0.f;
#pragma unroll
    for (int k = 0; k < 10; ++k) {
      a += p[k] * Wc[l * 10 + k];
      bb += p[k] * Wc[(l + 64) * 10 + k];
    }
    float mu = wsum(a + bb) * (1.f / HD);
    float v  = wsum(a * a + bb * bb) * (1.f / HD) - mu * mu;
    float rs = rsqrtf(v + 1e-5f);
    float va = (a - mu) * rs * g3v[l] + b3v[l];
    float vb = (bb - mu) * rs * g3v[l + 64] + b3v[l + 64];
    cbf[(size_t)r * HD + l]      = f2bf(va);
    cbf[(size_t)r * HD + l + 64] = f2bf(vb);
  } else {
    int i = (b - 25000) * 256 + threadIdx.x;
    if (i < 3 * HD * HD) wbf[i] = f2bf(Wih[i]);
  }
}

// ---------------- routing hop1 + fused normalize epilogue ------------------
__global__ __launch_bounds__(256) void routing1_kernel(
    const float* __restrict__ xn, const unsigned* __restrict__ xnb,
    const int* __restrict__ adj, float* __restrict__ out,
    float* __restrict__ onf, unsigned* __restrict__ onb) {
  __shared__ char zsh[4][4096];
  int tid = threadIdx.x;
  int w = tid >> 6, lane = tid & 63;
  int n = blockIdx.x * 4 + w;
  if (n >= N_IT) return;
  int m = lane & 15, quad = lane >> 4;
  const unsigned short* xb16 = (const unsigned short*)xnb;

  int idx = adj[n * MNB + m] - 1;
  const unsigned short* zrow = xb16 + (size_t)idx * HD;
  const unsigned short* xrow = xb16 + (size_t)n * HD;
  short8 zf[4], xf[4];
#pragma unroll
  for (int kk = 0; kk < 4; ++kk) {
    zf[kk] = *(const short8*)(zrow + kk * 32 + quad * 8);
    xf[kk] = *(const short8*)(xrow + kk * 32 + quad * 8);
  }
  f32x4 Gf = {0.f, 0.f, 0.f, 0.f}, Bv = {0.f, 0.f, 0.f, 0.f};
#pragma unroll
  for (int kk = 0; kk < 4; ++kk) {
    Gf = __builtin_amdgcn_mfma_f32_16x16x32_bf16(zf[kk], zf[kk], Gf, 0, 0, 0);
    Bv = __builtin_amdgcn_mfma_f32_16x16x32_bf16(zf[kk], xf[kk], Bv, 0, 0, 0);
  }
  char* zb = zsh[w] + m * 256;
#pragma unroll
  for (int kk = 0; kk < 4; ++kk)
    *(short8*)(zb + ((kk * 64 + quad * 16) ^ ((m & 7) << 4))) = zf[kk];

  float pc0 = 0.0625f, pc1 = 0.0625f, pc2 = 0.0625f, pc3 = 0.0625f;
  int msel = lane & 3;
  int cjaddr = (((lane >> 2) & 3) << 4 | (lane & 3)) << 2;

#pragma unroll
  for (int it = 0; it < 3; ++it) {
    float selv = (msel == 0) ? pc0 : (msel == 1) ? pc1 : (msel == 2) ? pc2 : pc3;
    float cj = __int_as_float(
        __builtin_amdgcn_ds_bpermute(cjaddr, __float_as_int(selv)));
    float g0 = Gf[0] * cj, g1 = Gf[1] * cj, g2 = Gf[2] * cj, g3 = Gf[3] * cj;
    g0 = dppadd<0xB1>(g0); g1 = dppadd<0xB1>(g1); g2 = dppadd<0xB1>(g2); g3 = dppadd<0xB1>(g3);
    g0 = dppadd<0x4E>(g0); g1 = dppadd<0x4E>(g1); g2 = dppadd<0x4E>(g2); g3 = dppadd<0x4E>(g3);
    g0 = swzadd<0x101F>(g0); g1 = swzadd<0x101F>(g1); g2 = swzadd<0x101F>(g2); g3 = swzadd<0x101F>(g3);
    g0 = swzadd<0x201F>(g0); g1 = swzadd<0x201F>(g1); g2 = swzadd<0x201F>(g2); g3 = swzadd<0x201F>(g3);
    float t1 = pc0 * g0 + pc1 * g1 + pc2 * g2 + pc3 * g3;
    float t2 = pc0 * Bv[0] + pc1 * Bv[1] + pc2 * Bv[2] + pc3 * Bv[3];
    t1 = swzadd<0x401F>(t1); t1 = bp32add(t1);
    t2 = swzadd<0x401F>(t2); t2 = bp32add(t2);
    float sq = fmaxf(1.f + 2.f * t2 + t1, 0.f);
    float s = (sq / (sq + 1.f)) / fmaxf(sqrtf(sq), 1e-12f);
    float e0 = __expf(s * (Bv[0] + g0));
    float e1 = __expf(s * (Bv[1] + g1));
    float e2 = __expf(s * (Bv[2] + g2));
    float e3 = __expf(s * (Bv[3] + g3));
    float se = e0 + e1 + e2 + e3;
    se = swzadd<0x401F>(se); se = bp32add(se);
    float inv = __fdividef(1.f, se);
    pc0 = e0 * inv; pc1 = e1 * inv; pc2 = e2 * inv; pc3 = e3 * inv;
  }
  float selv = (msel == 0) ? pc0 : (msel == 1) ? pc1 : (msel == 2) ? pc2 : pc3;
  float2 xv = *(const float2*)(xn + (size_t)n * HD + 2 * lane);
  float u0 = xv.x, u1 = xv.y;
#pragma unroll
  for (int mm = 0; mm < MNB; ++mm) {
    int srcl = ((((mm >> 2) << 4) | (mm & 3)) << 2);
    float pm = __int_as_float(
        __builtin_amdgcn_ds_bpermute(srcl, __float_as_int(selv)));
    unsigned zv = *(const unsigned*)(zsh[w] + mm * 256 +
                                     ((4 * lane) ^ ((mm & 7) << 4)));
    float z0 = __int_as_float((zv & 0xFFFFu) << 16);
    float z1 = __int_as_float((zv >> 16) << 16);
    u0 += z0 * pm;
    u1 += z1 * pm;
  }
  *(float2*)(out + (size_t)n * HD + 2 * lane) = make_float2(u0, u1);
  float nsq = wsum(u0 * u0 + u1 * u1);
  float ninv = 1.f / fmaxf(sqrtf(nsq), 1e-12f);
  float na = u0 * ninv, nb = u1 * ninv;
  *(float2*)(onf + (size_t)n * HD + 2 * lane) = make_float2(na, nb);
  onb[(size_t)n * 64 + lane] = (unsigned)f2bf(na) | ((unsigned)f2bf(nb) << 16);
}

// ---------------- routing v3 (hop2): verbatim ------------------------------
__global__ __launch_bounds__(256) void routing_kernel(
    const float* __restrict__ xn, const unsigned* __restrict__ xnb,
    const int* __restrict__ adj, float* __restrict__ out) {
  __shared__ char zsh[4][4096];
  int tid = threadIdx.x;
  int w = tid >> 6, lane = tid & 63;
  int n = blockIdx.x * 4 + w;
  if (n >= N_IT) return;
  int m = lane & 15, quad = lane >> 4;
  const unsigned short* xb16 = (const unsigned short*)xnb;

  int idx = adj[n * MNB + m] - 1;
  const unsigned short* zrow = xb16 + (size_t)idx * HD;
  const unsigned short* xrow = xb16 + (size_t)n * HD;
  short8 zf[4], xf[4];
#pragma unroll
  for (int kk = 0; kk < 4; ++kk) {
    zf[kk] = *(const short8*)(zrow + kk * 32 + quad * 8);
    xf[kk] = *(const short8*)(xrow + kk * 32 + quad * 8);
  }
  f32x4 Gf = {0.f, 0.f, 0.f, 0.f}, Bv = {0.f, 0.f, 0.f, 0.f};
#pragma unroll
  for (int kk = 0; kk < 4; ++kk) {
    Gf = __builtin_amdgcn_mfma_f32_16x16x32_bf16(zf[kk], zf[kk], Gf, 0, 0, 0);
    Bv = __builtin_amdgcn_mfma_f32_16x16x32_bf16(zf[kk], xf[kk], Bv, 0, 0, 0);
  }
  char* zb = zsh[w] + m * 256;
#pragma unroll
  for (int kk = 0; kk < 4; ++kk)
    *(short8*)(zb + ((kk * 64 + quad * 16) ^ ((m & 7) << 4))) = zf[kk];

  float pc0 = 0.0625f, pc1 = 0.0625f, pc2 = 0.0625f, pc3 = 0.0625f;
  int msel = lane & 3;
  int cjaddr = (((lane >> 2) & 3) << 4 | (lane & 3)) << 2;

#pragma unroll
  for (int it = 0; it < 3; ++it) {
    float selv = (msel == 0) ? pc0 : (msel == 1) ? pc1 : (msel == 2) ? pc2 : pc3;
    float cj = __int_as_float(
        __builtin_amdgcn_ds_bpermute(cjaddr, __float_as_int(selv)));
    float g0 = Gf[0] * cj, g1 = Gf[1] * cj, g2 = Gf[2] * cj, g3 = Gf[3] * cj;
    g0 = dppadd<0xB1>(g0); g1 = dppadd<0xB1>(g1); g2 = dppadd<0xB1>(g2); g3 = dppadd<0xB1>(g3);
    g0 = dppadd<0x4E>(g0); g1 = dppadd<0x4E>(g1); g2 = dppadd<0x4E>(g2); g3 = dppadd<0x4E>(g3);
    g0 = swzadd<0x101F>(g0); g1 = swzadd<0x101F>(g1); g2 = swzadd<0x101F>(g2); g3 = swzadd<0x101F>(g3);
    g0 = swzadd<0x201F>(g0); g1 = swzadd<0x201F>(g1); g2 = swzadd<0x201F>(g2); g3 = swzadd<0x201F>(g3);
    float t1 = pc0 * g0 + pc1 * g1 + pc2 * g2 + pc3 * g3;
    float t2 = pc0 * Bv[0] + pc1 * Bv[1] + pc2 * Bv[2] + pc3 * Bv[3];
    t1 = swzadd<0x401F>(t1); t1 = bp32add(t1);
    t2 = swzadd<0x401F>(t2); t2 = bp32add(t2);
    float sq = fmaxf(1.f + 2.f * t2 + t1, 0.f);
    float s = (sq / (sq + 1.f)) / fmaxf(sqrtf(sq), 1e-12f);
    float e0 = __expf(s * (Bv[0] + g0));
    float e1 = __expf(s * (Bv[1] + g1));
    float e2 = __expf(s * (Bv[2] + g2));
    float e3 = __expf(s * (Bv[3] + g3));
    float se = e0 + e1 + e2 + e3;
    se = swzadd<0x401F>(se); se = bp32add(se);
    float inv = __fdividef(1.f, se);
    pc0 = e0 * inv; pc1 = e1 * inv; pc2 = e2 * inv; pc3 = e3 * inv;
  }
  float selv = (msel == 0) ? pc0 : (msel == 1) ? pc1 : (msel == 2) ? pc2 : pc3;
  float2 xv = *(const float2*)(xn + (size_t)n * HD + 2 * lane);
  float u0 = xv.x, u1 = xv.y;
#pragma unroll
  for (int mm = 0; mm < MNB; ++mm) {
    int srcl = ((((mm >> 2) << 4) | (mm & 3)) << 2);
    float pm = __int_as_float(
        __builtin_amdgcn_ds_bpermute(srcl, __float_as_int(selv)));
    unsigned zv = *(const unsigned*)(zsh[w] + mm * 256 +
                                     ((4 * lane) ^ ((mm & 7) << 4)));
    float z0 = __int_as_float((zv & 0xFFFFu) << 16);
    float z1 = __int_as_float((zv >> 16) << 16);
    u0 += z0 * pm;
    u1 += z1 * pm;
  }
  *(float2*)(out + (size_t)n * HD + 2 * lane) = make_float2(u0, u1);
}

// ---------------- iv table: lane owns d={2l,2l+1}; packed dword out --------
__global__ void iv_kernel(const float* __restrict__ item_emb,
                          const float* __restrict__ o1, const float* __restrict__ o2,
                          const float* __restrict__ g, const float* __restrict__ bb,
                          unsigned* __restrict__ tbf2) {
  int w = threadIdx.x >> 6, l = threadIdx.x & 63;
  int r = blockIdx.x * 4 + w;
  if (r >= NI) return;
  if (r == 0) {
    tbf2[l] = 0;
    return;
  }
  size_t pr = (size_t)(r - 1) * HD + 2 * l;
  float2 iev = *(const float2*)(item_emb + (size_t)r * HD + 2 * l);
  float2 o1v = *(const float2*)(o1 + pr);
  float2 o2v = *(const float2*)(o2 + pr);
  float a = iev.x + o1v.x + o2v.x;
  float b = iev.y + o1v.y + o2v.y;
  float mu = wsum(a + b) * (1.f / HD);
  float v  = wsum(a * a + b * b) * (1.f / HD) - mu * mu;
  float rs = rsqrtf(v + 1e-5f);
  float2 gv = *(const float2*)(g + 2 * l);
  float2 bv = *(const float2*)(bb + 2 * l);
  float va = (a - mu) * rs * gv.x + bv.x;
  float vb = (b - mu) * rs * gv.y + bv.y;
  tbf2[(size_t)r * 64 + l] = (unsigned)f2bf(va) | ((unsigned)f2bf(vb) << 16);
}

// ---------------- gi via MFMA, bf16 out, LDS-staged coalesced writes -------
__global__ __launch_bounds__(256) void gi2_kernel(
    const unsigned short* __restrict__ tbf, const unsigned short* __restrict__ cbf,
    const int* __restrict__ sess, const unsigned short* __restrict__ wbf,
    unsigned short* __restrict__ gib) {
  __shared__ int sidx[16];
  __shared__ unsigned short gtile[16 * G3];  // 12 KB
  int tid = threadIdx.x;
  int row0 = blockIdx.x * 16;
  if (tid < 16) sidx[tid] = sess[(row0 + tid) % 25600];
  __syncthreads();
  const unsigned short* src = (row0 < 25600) ? tbf : cbf;
  int w = tid >> 6, lane = tid & 63;
  int rloc = lane & 15, quad = lane >> 4;
  int arow = sidx[rloc];
  int ko = quad * 8;
  short8 A[4];
#pragma unroll
  for (int kk = 0; kk < 4; ++kk)
    A[kk] = *(const short8*)(src + (size_t)arow * HD + kk * 32 + ko);
#pragma unroll
  for (int s = 0; s < 6; ++s) {
    int jt = w * 6 + s;
    int j = jt * 16 + rloc;
    f32x4 acc = {0.f, 0.f, 0.f, 0.f};
#pragma unroll
    for (int kk = 0; kk < 4; ++kk) {
      short8 B = *(const short8*)(wbf + (size_t)j * HD + kk * 32 + ko);
      acc = __builtin_amdgcn_mfma_f32_16x16x32_bf16(A[kk], B, acc, 0, 0, 0);
    }
#pragma unroll
    for (int q = 0; q < 4; ++q)
      gtile[(quad * 4 + q) * G3 + jt * 16 + rloc] = f2bf(acc[q]);
  }
  __syncthreads();
  const int4v* srcv = (const int4v*)gtile;
  int4v* dstv = (int4v*)(gib + (size_t)row0 * G3);
#pragma unroll
  for (int i = 0; i < 3; ++i)
    dstv[i * 256 + tid] = srcv[i * 256 + tid];
}

// ---------------- GRU recurrence via MFMA + fused LN epilogue --------------
// Snapshot h at t=len-1 into registers; after the t-loop stage fp32 via LDS
// and apply the (verbatim) ln_ht math per row, writing hbf directly.
__global__ __launch_bounds__(512) void gru_mfma_kernel(
    const unsigned short* __restrict__ gi_all, const float* __restrict__ Whh,
    const float* __restrict__ bih, const float* __restrict__ bhh,
    const int* __restrict__ lengths,
    const float* __restrict__ g2, const float* __restrict__ b2,
    const float* __restrict__ g4, const float* __restrict__ b4,
    unsigned short* __restrict__ hbf) {
  __shared__ unsigned short hlds[2][16 * HD];  // 8 KB
  __shared__ float hsn[16][HD];                // 8 KB (epilogue staging)
  int tid = threadIdx.x;
  int lane = tid & 63;
  int w = tid >> 6;
  int p = blockIdx.x >> 5;
  int r0 = (blockIdx.x & 31) * 16;
  int cN = lane & 15;
  int quad = lane >> 4;
  int d = w * 16 + cN;

  {
    int* hz = (int*)hlds;
    for (int i = tid; i < 2 * 16 * HD / 2; i += 512) hz[i] = 0;
  }

  short8 Br[4], Bz[4], Bn[4];
#pragma unroll
  for (int kk = 0; kk < 4; ++kk) {
    int kbase = quad * 8 + kk * 32;
    const float* wr_ = Whh + (size_t)d * HD + kbase;
    const float* wz_ = Whh + (size_t)(128 + d) * HD + kbase;
    const float* wn_ = Whh + (size_t)(256 + d) * HD + kbase;
    float4 r0v = *(const float4*)wr_, r1v = *(const float4*)(wr_ + 4);
    float4 z0v = *(const float4*)wz_, z1v = *(const float4*)(wz_ + 4);
    float4 n0v = *(const float4*)wn_, n1v = *(const float4*)(wn_ + 4);
    short8 br, bz, bn;
    br[0]=(short)f2bf(r0v.x); br[1]=(short)f2bf(r0v.y); br[2]=(short)f2bf(r0v.z); br[3]=(short)f2bf(r0v.w);
    br[4]=(short)f2bf(r1v.x); br[5]=(short)f2bf(r1v.y); br[6]=(short)f2bf(r1v.z); br[7]=(short)f2bf(r1v.w);
    bz[0]=(short)f2bf(z0v.x); bz[1]=(short)f2bf(z0v.y); bz[2]=(short)f2bf(z0v.z); bz[3]=(short)f2bf(z0v.w);
    bz[4]=(short)f2bf(z1v.x); bz[5]=(short)f2bf(z1v.y); bz[6]=(short)f2bf(z1v.z); bz[7]=(short)f2bf(z1v.w);
    bn[0]=(short)f2bf(n0v.x); bn[1]=(short)f2bf(n0v.y); bn[2]=(short)f2bf(n0v.z); bn[3]=(short)f2bf(n0v.w);
    bn[4]=(short)f2bf(n1v.x); bn[5]=(short)f2bf(n1v.y); bn[6]=(short)f2bf(n1v.z); bn[7]=(short)f2bf(n1v.w);
    Br[kk] = br; Bz[kk] = bz; Bn[kk] = bn;
  }
  float cr = bhh[d] + bih[d];
  float cz = bhh[128 + d] + bih[128 + d];
  float bhn = bhh[256 + d], bin = bih[256 + d];

  int lens4[4];
  float hold[4], hsnap[4];
  const unsigned short* gptr[4];
#pragma unroll
  for (int gq = 0; gq < 4; ++gq) {
    int lr = quad * 4 + gq;
    lens4[gq] = lengths[r0 + lr] - 1;
    hold[gq] = 0.f;
    hsnap[gq] = 0.f;
    gptr[gq] = gi_all + ((size_t)p * 25600 + (size_t)(r0 + lr) * LSEQ) * G3 + d;
  }

  int aoff[4];
#pragma unroll
  for (int kk = 0; kk < 4; ++kk)
    aoff[kk] = cN * 256 + (((quad * 8 + kk * 32) * 2) ^ ((cN & 7) << 4));
  int woff[4];
#pragma unroll
  for (int gq = 0; gq < 4; ++gq) {
    int lr = quad * 4 + gq;
    woff[gq] = lr * 256 + ((2 * d) ^ ((lr & 7) << 4));
  }

  float giaR[4], giaZ[4], giaN[4];
#pragma unroll
  for (int gq = 0; gq < 4; ++gq) {
    giaR[gq] = bf2f(gptr[gq][0]);
    giaZ[gq] = bf2f(gptr[gq][HD]);
    giaN[gq] = bf2f(gptr[gq][2 * HD]);
  }
  __syncthreads();

  for (int t = 0; t < LSEQ; ++t) {
    float gbR[4], gbZ[4], gbN[4];
#pragma unroll
    for (int gq = 0; gq < 4; ++gq) {
      const unsigned short* gp = gptr[gq] + (size_t)(t + 1) * G3;
      gbR[gq] = bf2f(gp[0]); gbZ[gq] = bf2f(gp[HD]); gbN[gq] = bf2f(gp[2 * HD]);
    }
    const char* hb = (const char*)hlds[t & 1];
    f32x4 accR = {0.f, 0.f, 0.f, 0.f};
    f32x4 accZ = {0.f, 0.f, 0.f, 0.f};
    f32x4 accN = {0.f, 0.f, 0.f, 0.f};
#pragma unroll
    for (int kk = 0; kk < 4; ++kk) {
      short8 A = *(const short8*)(hb + aoff[kk]);
      accR = __builtin_amdgcn_mfma_f32_16x16x32_bf16(A, Br[kk], accR, 0, 0, 0);
      accZ = __builtin_amdgcn_mfma_f32_16x16x32_bf16(A, Bz[kk], accZ, 0, 0, 0);
      accN = __builtin_amdgcn_mfma_f32_16x16x32_bf16(A, Bn[kk], accN, 0, 0, 0);
    }
    char* hw = (char*)hlds[(t + 1) & 1];
#pragma unroll
    for (int gq = 0; gq < 4; ++gq) {
      float rg = fast_sigm(giaR[gq] + accR[gq] + cr);
      float zg = fast_sigm(giaZ[gq] + accZ[gq] + cz);
      float ng = fast_tanh(giaN[gq] + bin + rg * (accN[gq] + bhn));
      float hnew = (1.f - zg) * ng + zg * hold[gq];
      hold[gq] = hnew;
      *(unsigned short*)(hw + woff[gq]) = f2bf(hnew);
      if (t == lens4[gq]) hsnap[gq] = hnew;
    }
    __syncthreads();
#pragma unroll
    for (int gq = 0; gq < 4; ++gq) {
      giaR[gq] = gbR[gq]; giaZ[gq] = gbZ[gq]; giaN[gq] = gbN[gq];
    }
  }

  // ---- fused LN epilogue (verbatim ln_ht math) ----
#pragma unroll
  for (int gq = 0; gq < 4; ++gq)
    hsn[quad * 4 + gq][d] = hsnap[gq];
  __syncthreads();
  const float* g = (p == 0) ? g2 : g4;
  const float* bb = (p == 0) ? b2 : b4;
#pragma unroll
  for (int rr = 0; rr < 2; ++rr) {
    int row = w * 2 + rr;
    float a = hsn[row][lane];
    float b = hsn[row][lane + 64];
    float mu = wsum(a + b) * (1.f / HD);
    float v  = wsum(a * a + b * b) * (1.f / HD) - mu * mu;
    float rs = rsqrtf(v + 1e-5f);
    float va = (a - mu) * rs * g[lane] + bb[lane];
    float vb = (b - mu) * rs * g[lane + 64] + bb[lane + 64];
    size_t ro = (size_t)(p * BSZ + r0 + row) * HD;
    hbf[ro + lane]      = f2bf(va);
    hbf[ro + lane + 64] = f2bf(vb);
  }
}

// ---------------- scores: B-reuse x4 row-groups per block ------------------
#define JW 256
__global__ __launch_bounds__(512) void scores3_kernel(
    const unsigned short* __restrict__ hbf,
    const unsigned short* __restrict__ tbf,
    const unsigned short* __restrict__ cbf,
    const float* __restrict__ a1p, const float* __restrict__ a2p,
    float* __restrict__ out) {
  __shared__ float s1l[32 * JW];
  __shared__ float s2l[32 * JW];
  int tid = threadIdx.x;
  int w = tid >> 6, lane = tid & 63;
  int strip = blockIdx.x >> 2;
  int rq = blockIdx.x & 3;
  int j0 = strip * JW;
  int jc = j0 + w * 32 + (lane & 31);
  int jl = (jc < N_IT) ? jc : (N_IT - 1);
  int koA = (lane >> 5) * 8;

  short8 B1[8], B2[8];
  const unsigned short* b1p = tbf + (size_t)(jl + 1) * HD + koA;
  const unsigned short* b2p = cbf + (size_t)(jl + 1) * HD + koA;
#pragma unroll
  for (int kk = 0; kk < 8; ++kk) {
    B1[kk] = *(const short8*)(b1p + kk * 16);
    B2[kk] = *(const short8*)(b2p + kk * 16);
  }
  float sa1 = sigmf(a1p[0]);
  float sa2 = sigmf(a2p[0]);
  const size_t S = (size_t)BSZ * N_IT;
  int colb = w * 32 + (lane & 31);
  bool full = (j0 + JW <= N_IT);

  for (int ps = 0; ps < 4; ++ps) {
    int r0b = rq * 128 + ps * 32;
    f32x16 acc1 = {0.f}, acc2 = {0.f};
    const unsigned short* h1p = hbf + (size_t)(r0b + (lane & 31)) * HD + koA;
    const unsigned short* h2p = h1p + (size_t)BSZ * HD;
#pragma unroll
    for (int kk = 0; kk < 8; ++kk) {
      short8 A1 = *(const short8*)(h1p + kk * 16);
      short8 A2 = *(const short8*)(h2p + kk * 16);
      acc1 = __builtin_amdgcn_mfma_f32_32x32x16_bf16(A1, B1[kk], acc1, 0, 0, 0);
      acc2 = __builtin_amdgcn_mfma_f32_32x32x16_bf16(A2, B2[kk], acc2, 0, 0, 0);
    }
#pragma unroll
    for (int q = 0; q < 16; ++q) {
      int row = (q & 3) + 8 * (q >> 2) + 4 * (lane >> 5);
      s1l[row * JW + colb] = acc1[q];
      s2l[row * JW + colb] = acc2[q];
    }
    __syncthreads();

    if (full) {
#pragma unroll
      for (int pss = 0; pss < 16; ++pss) {
        int idx = pss * 512 + tid;
        int row = idx >> 8;
        int jlc = idx & 255;
        float s1 = s1l[idx];
        float s2 = s2l[idx];
        size_t o = (size_t)(r0b + row) * N_IT + j0 + jlc;
        out[o]         = sa1 * s1 + sa2 * s2;
        out[S + o]     = s1;
        out[2 * S + o] = s2;
      }
    } else {
#pragma unroll
      for (int pss = 0; pss < 16; ++pss) {
        int idx = pss * 512 + tid;
        int row = idx >> 8;
        int jlc = idx & 255;
        int jg = j0 + jlc;
        if (jg < N_IT) {
          float s1 = s1l[idx];
          float s2 = s2l[idx];
          size_t o = (size_t)(r0b + row) * N_IT + jg;
          out[o]         = sa1 * s1 + sa2 * s2;
          out[S + o]     = s1;
          out[2 * S + o] = s2;
        }
      }
    }
    __syncthreads();
  }
}

extern "C" void kernel_launch(void* const* d_in, const int* in_sizes, int n_in,
                              void* d_out, int out_size, void* d_ws, size_t ws_size,
                              hipStream_t stream) {
  const float* item_emb = (const float*)d_in[0];
  const float* prob_emb = (const float*)d_in[1];
  const float* W_cls    = (const float*)d_in[2];
  const float* a1       = (const float*)d_in[3];
  const float* a2       = (const float*)d_in[4];
  const float* Wih      = (const float*)d_in[5];
  const float* Whh      = (const float*)d_in[6];
  const float* bih      = (const float*)d_in[7];
  const float* bhh      = (const float*)d_in[8];
  const float* ln1_g = (const float*)d_in[9];
  const float* ln1_b = (const float*)d_in[10];
  const float* ln2_g = (const float*)d_in[11];
  const float* ln2_b = (const float*)d_in[12];
  const float* ln3_g = (const float*)d_in[13];
  const float* ln3_b = (const float*)d_in[14];
  const float* ln4_g = (const float*)d_in[15];
  const float* ln4_b = (const float*)d_in[16];
  const int* inp_sess = (const int*)d_in[19];
  const int* lengths  = (const int*)d_in[20];
  const int* adj      = (const int*)d_in[21];
  float* out = (float*)d_out;

  // Layout identical to R15-R17 (lifetime-audited). htb slot now unused.
  float* ws = (float*)d_ws;
  const size_t SZ_ROW = (size_t)N_IT * HD;
  float* xn   = ws;
  float* o1   = xn + SZ_ROW;
  float* o2   = o1 + SZ_ROW;
  float* slot = o2 + SZ_ROW;
  float* x1f  = slot;
  unsigned* x1b = (unsigned*)(slot + 6400000);
  unsigned short* cbf = (unsigned short*)(slot + 9600000);
  float* gi  = slot + 2 * (size_t)NI * HD;

  unsigned* xnb = (unsigned*)gi;
  unsigned short* gib = (unsigned short*)gi;
  unsigned short* wbf = (unsigned short*)(gi + 10000000);
  unsigned short* tbf = (unsigned short*)xn;
  unsigned short* hbf = (unsigned short*)o1;   // written by gru epilogue (o1 dead after iv)

  int nb4 = (N_IT + 3) / 4;
  int nb4i = (NI + 3) / 4;

  prelude_kernel<<<25192, 256, 0, stream>>>(item_emb, xn, xnb,
                                            prob_emb, W_cls, ln3_g, ln3_b, cbf,
                                            Wih, wbf);
  routing1_kernel<<<nb4, 256, 0, stream>>>(xn, xnb, adj + MNB, o1, x1f, x1b);
  routing_kernel<<<nb4, 256, 0, stream>>>(x1f, x1b, adj + MNB, o2);
  iv_kernel<<<nb4i, 256, 0, stream>>>(item_emb, o1, o2, ln1_g, ln1_b,
                                      (unsigned*)tbf);
  gi2_kernel<<<3200, 256, 0, stream>>>(tbf, cbf, inp_sess, wbf, gib);
  gru_mfma_kernel<<<64, 512, 0, stream>>>(gib, Whh, bih, bhh, lengths,
                                          ln2_g, ln2_b, ln4_g, ln4_b, hbf);
  scores3_kernel<<<196 * 4, 512, 0, stream>>>(hbf, tbf, cbf, a1, a2, out);
}